// Round 5
// baseline (3611.881 us; speedup 1.0000x reference)
//
#include <hip/hip_runtime.h>
#include <math.h>

typedef unsigned short u16;
typedef unsigned int   u32;
typedef __attribute__((ext_vector_type(8))) short short8;
typedef __attribute__((ext_vector_type(4))) float f32x4;

#define NT 64
#define OC 580
#define SLC 20480                       // u16 per slice (40 KB)
#define NSLICE 19
#define P_EB    (NSLICE * SLC)          // 389120: epre B frags [ks32][tt13]x512
#define P_WP1   (P_EB + 32 * 13 * 512)  // 602112: Wp1 [ks7][tt13]x512
#define P_WP2   (P_WP1 + 7 * 13 * 512)  // 648704: Wp2 [ks7][tt4]x512
#define P_TOTAL (P_WP2 + 7 * 4 * 512)   // 663040 u16 = 1.33 MB

__device__ __forceinline__ float elu_f(float x) { return x > 0.f ? x : __expf(x) - 1.f; }
__device__ __forceinline__ float sig_f(float x) { return 1.f / (1.f + __expf(-x)); }
__device__ __forceinline__ float sp_f(float x)  { return x > 20.f ? x : log1pf(__expf(x)); }

__device__ __forceinline__ u16 f2b(float f) {   // f32 -> bf16 RNE
    union { float f; u32 u; } v; v.f = f;
    u32 r = (v.u + 0x7fffu + ((v.u >> 16) & 1u)) >> 16;
    return (u16)r;
}

__device__ __forceinline__ short8 pack8(float4 v0, float4 v1) {
    short8 r;
    r[0] = (short)f2b(v0.x); r[1] = (short)f2b(v0.y);
    r[2] = (short)f2b(v0.z); r[3] = (short)f2b(v0.w);
    r[4] = (short)f2b(v1.x); r[5] = (short)f2b(v1.y);
    r[6] = (short)f2b(v1.z); r[7] = (short)f2b(v1.w);
    return r;
}

#define MFMA(a, b, c) __builtin_amdgcn_mfma_f32_16x16x32_bf16((a), (b), (c), 0, 0, 0)

// ---------------------------------------------------------------------------
// prep: pack weights to bf16 MFMA B-fragments (512 u16 each):
// frag[ln][e] = W[n0+(ln&15)][k0+(ln>>4)*8+e], zero-padded.
// Scan stream = 19 slices of 40 KB in exact per-step consumption order.
// ---------------------------------------------------------------------------
__global__ __launch_bounds__(256) void prep_pack(
    const float* __restrict__ Wi, const float* __restrict__ W_ih,
    const float* __restrict__ W_hh, const float* __restrict__ Wq1,
    const float* __restrict__ Wq2, const float* __restrict__ Wp1,
    const float* __restrict__ Wp2, u16* __restrict__ wp)
{
    for (size_t r = (size_t)blockIdx.x * 256 + threadIdx.x; r < P_TOTAL;
         r += (size_t)gridDim.x * 256) {
        float val = 0.f;
        if (r < P_EB) {
            int s = (int)(r / SLC), rem = (int)(r % SLC);
            int f = rem >> 9, ln = (rem >> 3) & 63, e = rem & 7;
            int row = ln & 15, kg = ln >> 4;
            if (s == 0) {                               // phase A: Wi [200x36]
                if (f < 26) {
                    int tt = f >> 1, ks = f & 1;
                    int j = tt * 16 + row, k = ks * 32 + kg * 8 + e;
                    if (j < 200 && k < 36) val = Wi[j * 36 + k];
                }
            } else if (s <= 14) {                       // phase B: W_ih/W_hh
                int ks = (s - 1) >> 1, h = (s - 1) & 1;
                int nf = h ? 38 : 40;
                if (f < nf) {
                    int u = (h ? 20 : 0) + (f >> 1), m = f & 1;
                    int g = u / 13, tt = u % 13;
                    int j = tt * 16 + row, k = ks * 32 + kg * 8 + e;
                    if (j < 200 && k < 200)
                        val = m ? W_hh[(size_t)(g * 200 + j) * 200 + k]
                                : W_ih[(size_t)(g * 200 + j) * 200 + k];
                }
            } else if (s <= 17) {                       // phase C: Wq1[:, :200]
                int c = s - 15;
                int ks0 = (c == 0) ? 0 : (c == 1 ? 2 : 5);
                int nks = (c == 1) ? 3 : 2;
                if (f < nks * 13) {
                    int ks = ks0 + f / 13, tt = f % 13;
                    int j = tt * 16 + row, k = ks * 32 + kg * 8 + e;
                    if (j < 200 && k < 200) val = Wq1[(size_t)j * 1224 + k];
                }
            } else {                                    // phase D: Wq2 [60x200]
                if (f < 28) {
                    int tt = f / 7, ks = f % 7;
                    int j = tt * 16 + row, k = ks * 32 + kg * 8 + e;
                    if (j < 60 && k < 200) val = Wq2[(size_t)j * 200 + k];
                }
            }
        } else if (r < P_WP1) {                         // epre: Wq1[:,200:1224]
            size_t q = r - P_EB;
            int frag = (int)(q >> 9), ln = (int)((q >> 3) & 63), e = (int)(q & 7);
            int ks = frag / 13, tt = frag % 13;
            int j = tt * 16 + (ln & 15), k = ks * 32 + (ln >> 4) * 8 + e;
            if (j < 200) val = Wq1[(size_t)j * 1224 + 200 + k];
        } else if (r < P_WP2) {                         // Wp1 [200x200]
            size_t q = r - P_WP1;
            int frag = (int)(q >> 9), ln = (int)((q >> 3) & 63), e = (int)(q & 7);
            int ks = frag / 13, tt = frag % 13;
            int j = tt * 16 + (ln & 15), k = ks * 32 + (ln >> 4) * 8 + e;
            if (j < 200 && k < 200) val = Wp1[(size_t)j * 200 + k];
        } else {                                        // Wp2 [60x200]
            size_t q = r - P_WP2;
            int frag = (int)(q >> 9), ln = (int)((q >> 3) & 63), e = (int)(q & 7);
            int ks = frag / 4, tt = frag % 4;
            int j = tt * 16 + (ln & 15), k = ks * 32 + (ln >> 4) * 8 + e;
            if (j < 60 && k < 200) val = Wp2[(size_t)j * 200 + k];
        }
        wp[r] = f2b(val);
    }
}

// ---------------------------------------------------------------------------
// Epre (MFMA): out[bt*580+290+j] = embed[bt] . Wq1[j][200:] + bq1[j]
// ---------------------------------------------------------------------------
__global__ __launch_bounds__(512) void epre_mfma(
    const float* __restrict__ embed, const u16* __restrict__ wp,
    const float* __restrict__ bq1, float* __restrict__ out)
{
    const int tid = threadIdx.x;
    const int wv = tid >> 6, ln = tid & 63;
    const int arow = ln & 15, kgrp = ln >> 4;
    const int m0 = blockIdx.x * 256 + wv * 32;

    f32x4 acc[2][13];
    #pragma unroll
    for (int tt = 0; tt < 13; ++tt) {
        const int j = tt * 16 + arow;
        const float bv = (j < 200) ? bq1[j] : 0.f;
        acc[0][tt] = (f32x4){bv, bv, bv, bv};
        acc[1][tt] = acc[0][tt];
    }
    const float* e0 = &embed[(size_t)(m0 + arow) * 1024 + kgrp * 8];
    const float* e1 = e0 + (size_t)16 * 1024;

    for (int ks = 0; ks < 32; ++ks) {
        short8 a0, a1;
        {
            float4 v0 = *(const float4*)(e0 + ks * 32);
            float4 v1 = *(const float4*)(e0 + ks * 32 + 4);
            a0 = pack8(v0, v1);
            float4 w0 = *(const float4*)(e1 + ks * 32);
            float4 w1 = *(const float4*)(e1 + ks * 32 + 4);
            a1 = pack8(w0, w1);
        }
        const u16* bp = &wp[P_EB + (size_t)ks * 13 * 512 + (size_t)ln * 8];
        #pragma unroll
        for (int tt = 0; tt < 13; ++tt) {
            short8 b = *(const short8*)(bp + (size_t)tt * 512);
            acc[0][tt] = MFMA(a0, b, acc[0][tt]);
            acc[1][tt] = MFMA(a1, b, acc[1][tt]);
        }
    }
    #pragma unroll
    for (int f = 0; f < 2; ++f) {
        const size_t rbase = (size_t)(m0 + f * 16 + kgrp * 4);
        #pragma unroll
        for (int tt = 0; tt < 13; ++tt) {
            const int j = tt * 16 + arow;
            if (j < 200) {
                #pragma unroll
                for (int e = 0; e < 4; ++e)
                    out[(rbase + e) * OC + 290 + j] = acc[f][tt][e];
            }
        }
    }
}

// ---------------------------------------------------------------------------
// Scan: 64 blocks x 16 rows x 512 thr. Sliced LDS double-buffered weight
// stream (19 x 40KB slices/step), issue-early/write-late reg staging.
// ---------------------------------------------------------------------------
__global__ __launch_bounds__(512, 2) void scan_mfma(
    const float* __restrict__ action, const float* __restrict__ noise_post,
    const float* __restrict__ b_ih, const float* __restrict__ b_hh,
    const float* __restrict__ bi, const float* __restrict__ bq2,
    const u16* __restrict__ wp, float* __restrict__ out)
{
    __shared__ __align__(16) u16      s_wb[2][SLC];      // 80 KB weight dbuf
    __shared__ __align__(16) u16      s_in0[16][64];     // [stoch30|act6|pad]
    __shared__ __align__(16) u16      s_x[16][232];
    __shared__ __align__(16) u16      s_db[2][16][232];  // deter bf16 dbuf
    __shared__ __align__(16) u16      s_hq[16][232];
    __shared__ __align__(16) _Float16 s_rz[2][16][208];  // r,z gates (f16)
    __shared__ __align__(16) float    s_df[16][208];     // deter f32 carry
    __shared__ __align__(16) float    s_ep[16][208];     // Epre staged
    __shared__ __align__(16) float    s_q[16][64];

    const int tid  = threadIdx.x;
    const int wv   = tid >> 6, ln = tid & 63;
    const int arow = ln & 15, kgrp = ln >> 4;
    const int b0   = blockIdx.x * 16;

    // ---- unit tables + bias seeds (registers, once) ----
    int uu[5], ug[5], uj[5]; bool uv[5];
    float seedA[5], seedN[5];
    #pragma unroll
    for (int q = 0; q < 5; ++q) {
        int u = wv + 8 * q;
        uv[q] = (u < 39); uu[q] = u;
        int ue = uv[q] ? u : 0;
        ug[q] = ue / 13;
        int tt = ue % 13;
        uj[q] = tt * 16 + arow;
        float sa = 0.f, sn = 0.f;
        if (uv[q] && uj[q] < 200) {
            if (ug[q] < 2) sa = b_ih[ug[q] * 200 + uj[q]] + b_hh[ug[q] * 200 + uj[q]];
            else { sa = b_ih[400 + uj[q]]; sn = b_hh[400 + uj[q]]; }
        }
        seedA[q] = sa; seedN[q] = sn;
    }
    const int tA0 = wv, tA1 = wv + 8;
    const float biA0 = bi[tA0 * 16 + arow];
    const float biA1 = (tA1 < 13 && (tA1 * 16 + arow) < 200) ? bi[tA1 * 16 + arow] : 0.f;
    const float bD = (wv < 4 && (wv * 16 + arow) < 60) ? bq2[wv * 16 + arow] : 0.f;

    // ---- zero-init activation LDS ----
    { u32* z = (u32*)s_in0; for (int i = tid; i < 16 * 64 / 2; i += 512) z[i] = 0; }
    { u32* z = (u32*)s_x;   for (int i = tid; i < 16 * 232 / 2; i += 512) z[i] = 0; }
    { u32* z = (u32*)s_db;  for (int i = tid; i < 2 * 16 * 232 / 2; i += 512) z[i] = 0; }
    { u32* z = (u32*)s_hq;  for (int i = tid; i < 16 * 232 / 2; i += 512) z[i] = 0; }
    { float* z = (float*)s_df; for (int i = tid; i < 16 * 208; i += 512) z[i] = 0.f; }
    { float* z = (float*)s_ep; for (int i = tid; i < 16 * 208; i += 512) z[i] = 0.f; }
    __syncthreads();   // FIX (r4 bug): zero-init must complete before prologue staging

    // ---- prologue: stage slice 0 + Epre(0) + action(0) ----
    {
        float4 st[5];
        const u16* gp = wp + (size_t)tid * 8;
        #pragma unroll
        for (int r = 0; r < 5; ++r) st[r] = *(const float4*)(gp + r * 4096);
        for (int idx = tid; idx < 16 * 200; idx += 512) {
            int i = idx / 200, j = idx - i * 200;
            s_ep[i][j] = out[((size_t)(b0 + i) * NT + 0) * OC + 290 + j];
        }
        if (tid < 96) {
            int i = tid / 6, c = tid - i * 6;
            s_in0[i][30 + c] = f2b(action[((size_t)(b0 + i) * NT + 0) * 6 + c]);
        }
        u16* lp = &s_wb[0][0] + (size_t)tid * 8;
        #pragma unroll
        for (int r = 0; r < 5; ++r) *(float4*)(lp + r * 4096) = st[r];
        __syncthreads();
    }

    float4 stg[5];
    int kb = 0, cur = 0;

#define STAGE_ISSUE(sl) { const u16* gp_ = wp + (size_t)(sl) * SLC + (size_t)tid * 8; \
    _Pragma("unroll") for (int r_ = 0; r_ < 5; ++r_) stg[r_] = *(const float4*)(gp_ + r_ * 4096); }
#define STAGE_WRITE() { u16* lp_ = &s_wb[(kb + 1) & 1][0] + (size_t)tid * 8; \
    _Pragma("unroll") for (int r_ = 0; r_ < 5; ++r_) *(float4*)(lp_ + r_ * 4096) = stg[r_]; }

    for (int t = 0; t < NT; ++t) {
        f32x4 accA[5], accN[5], accC0, accC1;

        // ======== iter A: x = elu([stoch|act] @ Wi^T + bi), slice 0 ========
        {
            STAGE_ISSUE(1);
            const u16* cb = &s_wb[kb & 1][0];
            short8 af0 = *(const short8*)&s_in0[arow][kgrp * 8];
            short8 af1 = *(const short8*)&s_in0[arow][32 + kgrp * 8];
            f32x4 a0 = {biA0, biA0, biA0, biA0};
            a0 = MFMA(af0, *(const short8*)(cb + (tA0 * 2 + 0) * 512 + ln * 8), a0);
            a0 = MFMA(af1, *(const short8*)(cb + (tA0 * 2 + 1) * 512 + ln * 8), a0);
            #pragma unroll
            for (int e = 0; e < 4; ++e)
                s_x[kgrp * 4 + e][tA0 * 16 + arow] = f2b(elu_f(a0[e]));
            if (tA1 < 13) {
                f32x4 a1 = {biA1, biA1, biA1, biA1};
                a1 = MFMA(af0, *(const short8*)(cb + (tA1 * 2 + 0) * 512 + ln * 8), a1);
                a1 = MFMA(af1, *(const short8*)(cb + (tA1 * 2 + 1) * 512 + ln * 8), a1);
                #pragma unroll
                for (int e = 0; e < 4; ++e)
                    s_x[kgrp * 4 + e][tA1 * 16 + arow] = f2b(elu_f(a1[e]));
            }
            STAGE_WRITE(); __syncthreads(); ++kb;
        }

        // ======== iters B1..B14: GRU gates, slices 1..14 ========
        #pragma unroll
        for (int q = 0; q < 5; ++q) {
            accA[q] = (f32x4){seedA[q], seedA[q], seedA[q], seedA[q]};
            accN[q] = (f32x4){seedN[q], seedN[q], seedN[q], seedN[q]};
        }
        for (int ks = 0; ks < 7; ++ks) {
            short8 ax = *(const short8*)&s_x[arow][ks * 32 + kgrp * 8];
            short8 ad = *(const short8*)&s_db[cur][arow][ks * 32 + kgrp * 8];
            for (int h = 0; h < 2; ++h) {
                const int s = 1 + ks * 2 + h;
                STAGE_ISSUE(s + 1);
                const u16* cb = &s_wb[kb & 1][0];
                #pragma unroll
                for (int q = 0; q < 5; ++q) {
                    const int u = wv + 8 * q;
                    const bool inh = uv[q] && ((h == 0) ? (u < 20) : (u >= 20));
                    if (inh) {
                        const int fb = ((h ? (u - 20) : u) * 2) * 512;
                        short8 wih = *(const short8*)(cb + fb + ln * 8);
                        short8 whh = *(const short8*)(cb + fb + 512 + ln * 8);
                        if (ug[q] < 2) {
                            accA[q] = MFMA(ax, wih, accA[q]);
                            accA[q] = MFMA(ad, whh, accA[q]);
                        } else {
                            accA[q] = MFMA(ax, wih, accA[q]);
                            accN[q] = MFMA(ad, whh, accN[q]);
                        }
                    }
                }
                if (ks == 6 && h == 1) {   // r/z owners publish sigma(acc) as f16
                    #pragma unroll
                    for (int q = 0; q < 5; ++q)
                        if (uv[q] && uu[q] < 26) {
                            #pragma unroll
                            for (int e = 0; e < 4; ++e)
                                s_rz[ug[q]][kgrp * 4 + e][uj[q]] =
                                    (_Float16)sig_f(accA[q][e]);
                        }
                }
                STAGE_WRITE(); __syncthreads(); ++kb;
            }
        }

        // ======== combine iter (no slice): n-owners update deter ========
        {
            #pragma unroll
            for (int e = 0; e < 4; ++e) {
                accC0[e] = s_ep[kgrp * 4 + e][tA0 * 16 + arow];
                accC1[e] = (tA1 < 13) ? s_ep[kgrp * 4 + e][tA1 * 16 + arow] : 0.f;
            }
            #pragma unroll
            for (int q = 0; q < 5; ++q)
                if (uv[q] && uu[q] >= 26) {
                    const int j = uj[q];
                    #pragma unroll
                    for (int e = 0; e < 4; ++e) {
                        const int i = kgrp * 4 + e;
                        float rr = (float)s_rz[0][i][j];
                        float zz = (float)s_rz[1][i][j];
                        float dold = s_df[i][j];
                        float nn = tanhf(accA[q][e] + rr * accN[q][e]);
                        float d = (1.f - zz) * nn + zz * dold;
                        s_df[i][j] = d;
                        s_db[cur ^ 1][i][j] = f2b(d);
                    }
                }
            __syncthreads();
        }

        // ======== iters C0..C2: hq = elu(deter_new @ Wq1a^T + Epre) ========
        {
            const int ks0c[3] = {0, 2, 5};
            const int nksc[3] = {2, 3, 2};
            #pragma unroll
            for (int c = 0; c < 3; ++c) {
                const int s = 15 + c;
                STAGE_ISSUE(s + 1 <= 18 ? s + 1 : 0);
                const u16* cb = &s_wb[kb & 1][0];
                for (int kl = 0; kl < nksc[c]; ++kl) {
                    const int ks = ks0c[c] + kl;
                    short8 adn = *(const short8*)&s_db[cur ^ 1][arow][ks * 32 + kgrp * 8];
                    accC0 = MFMA(adn, *(const short8*)(cb + (kl * 13 + tA0) * 512 + ln * 8), accC0);
                    if (tA1 < 13)
                        accC1 = MFMA(adn, *(const short8*)(cb + (kl * 13 + tA1) * 512 + ln * 8), accC1);
                }
                if (c == 2) {
                    #pragma unroll
                    for (int e = 0; e < 4; ++e)
                        s_hq[kgrp * 4 + e][tA0 * 16 + arow] = f2b(elu_f(accC0[e]));
                    if (tA1 < 13) {
                        #pragma unroll
                        for (int e = 0; e < 4; ++e)
                            s_hq[kgrp * 4 + e][tA1 * 16 + arow] = f2b(elu_f(accC1[e]));
                    }
                }
                STAGE_WRITE(); __syncthreads(); ++kb;
            }
        }

        // ======== iter D: q = hq @ Wq2^T + bq2, slice 18 ========
        {
            STAGE_ISSUE(0);   // slice 0 for t+1
            const u16* cb = &s_wb[kb & 1][0];
            if (wv < 4) {
                f32x4 aq = {bD, bD, bD, bD};
                #pragma unroll
                for (int ks = 0; ks < 7; ++ks) {
                    short8 ah = *(const short8*)&s_hq[arow][ks * 32 + kgrp * 8];
                    aq = MFMA(ah, *(const short8*)(cb + (wv * 7 + ks) * 512 + ln * 8), aq);
                }
                #pragma unroll
                for (int e = 0; e < 4; ++e) s_q[kgrp * 4 + e][wv * 16 + arow] = aq[e];
            }
            STAGE_WRITE(); __syncthreads(); ++kb;
        }

        // ======== iter D2: sample + global writes + stage t+1 ========
        {
            if (tid < 480) {
                int i = tid / 30, ss = tid - i * 30;
                float qm = s_q[i][ss];
                float qs = sp_f(s_q[i][30 + ss]) + 0.1f;
                size_t bt = (size_t)(b0 + i) * NT + t;
                float qst = noise_post[bt * 30 + ss] * qs + qm;
                size_t o = bt * OC;
                out[o + ss]      = qm;
                out[o + 30 + ss] = qs;
                out[o + 60 + ss] = qst;
                s_in0[i][ss] = f2b(qst);
            }
            for (int idx = tid; idx < 16 * 200; idx += 512) {
                int i = idx / 200, j = idx - i * 200;
                float d = s_df[i][j];
                size_t o = ((size_t)(b0 + i) * NT + t) * OC;
                out[o + 90 + j]  = d;
                out[o + 380 + j] = d;
            }
            if (t + 1 < NT) {
                for (int idx = tid; idx < 16 * 200; idx += 512) {
                    int i = idx / 200, j = idx - i * 200;
                    s_ep[i][j] = out[((size_t)(b0 + i) * NT + (t + 1)) * OC + 290 + j];
                }
                if (tid < 96) {
                    int i = tid / 6, c = tid - i * 6;
                    s_in0[i][30 + c] = f2b(action[((size_t)(b0 + i) * NT + (t + 1)) * 6 + c]);
                }
            }
            __syncthreads();
        }
        cur ^= 1;
    }
#undef STAGE_ISSUE
#undef STAGE_WRITE
}

// ---------------------------------------------------------------------------
// Prior head (MFMA): 1024 blocks x 64 bt-rows, 256 thr (4 waves x 16 rows).
// ---------------------------------------------------------------------------
__global__ __launch_bounds__(256) void prior_mfma(
    const float* __restrict__ noise_prior, const u16* __restrict__ wp,
    const float* __restrict__ bp1, const float* __restrict__ bp2,
    float* __restrict__ out)
{
    __shared__ __align__(16) u16   s_hp[64][232];
    __shared__ __align__(16) float s_p[64][68];
    const int tid = threadIdx.x;
    const int wv = tid >> 6, ln = tid & 63;
    const int arow = ln & 15, kgrp = ln >> 4;
    const size_t bt0 = (size_t)blockIdx.x * 64;
    const int m0 = wv * 16;

    for (int idx = tid; idx < 64 * 32; idx += 256) {   // zero pad cols 200..231
        int r2 = idx >> 5, c = 200 + (idx & 31);
        s_hp[r2][c] = 0;
    }

    // GEMM1: hp = elu(deter @ Wp1^T + bp1)
    f32x4 acc[13];
    #pragma unroll
    for (int tt = 0; tt < 13; ++tt) {
        const int j = tt * 16 + arow;
        const float bv = (j < 200) ? bp1[j] : 0.f;
        acc[tt] = (f32x4){bv, bv, bv, bv};
    }
    for (int ks = 0; ks < 7; ++ks) {
        short8 a;
        const int k0 = ks * 32 + kgrp * 8;
        if (k0 <= 192) {
            const float* dp = &out[(bt0 + m0 + arow) * OC + 380 + k0];
            float4 v0 = *(const float4*)dp;
            float4 v1 = *(const float4*)(dp + 4);
            a = pack8(v0, v1);
        } else {
            a = (short8){0, 0, 0, 0, 0, 0, 0, 0};
        }
        const u16* bp = &wp[P_WP1 + (size_t)ks * 13 * 512 + (size_t)ln * 8];
        #pragma unroll
        for (int tt = 0; tt < 13; ++tt)
            acc[tt] = MFMA(a, *(const short8*)(bp + (size_t)tt * 512), acc[tt]);
    }
    #pragma unroll
    for (int tt = 0; tt < 13; ++tt)
        #pragma unroll
        for (int e = 0; e < 4; ++e)
            s_hp[m0 + kgrp * 4 + e][tt * 16 + arow] = f2b(elu_f(acc[tt][e]));
    __syncthreads();

    // GEMM2: p = hp @ Wp2^T + bp2
    f32x4 acc2[4];
    #pragma unroll
    for (int tt = 0; tt < 4; ++tt) {
        const int j = tt * 16 + arow;
        const float bv = (j < 60) ? bp2[j] : 0.f;
        acc2[tt] = (f32x4){bv, bv, bv, bv};
    }
    #pragma unroll
    for (int ks = 0; ks < 7; ++ks) {
        short8 ah = *(const short8*)&s_hp[m0 + arow][ks * 32 + kgrp * 8];
        const u16* bp = &wp[P_WP2 + (size_t)ks * 4 * 512 + (size_t)ln * 8];
        #pragma unroll
        for (int tt = 0; tt < 4; ++tt)
            acc2[tt] = MFMA(ah, *(const short8*)(bp + (size_t)tt * 512), acc2[tt]);
    }
    #pragma unroll
    for (int tt = 0; tt < 4; ++tt)
        #pragma unroll
        for (int e = 0; e < 4; ++e)
            s_p[m0 + kgrp * 4 + e][tt * 16 + arow] = acc2[tt][e];
    __syncthreads();

    for (int idx = tid; idx < 64 * 30; idx += 256) {
        int i = idx / 30, ss = idx - i * 30;
        float pm = s_p[i][ss];
        float ps = sp_f(s_p[i][30 + ss]) + 0.1f;
        float pst = noise_prior[(bt0 + i) * 30 + ss] * ps + pm;
        size_t base = (bt0 + i) * OC;
        out[base + 290 + ss] = pm;
        out[base + 320 + ss] = ps;
        out[base + 350 + ss] = pst;
    }
}

extern "C" void kernel_launch(void* const* d_in, const int* in_sizes, int n_in,
                              void* d_out, int out_size, void* d_ws, size_t ws_size,
                              hipStream_t stream)
{
    (void)in_sizes; (void)n_in; (void)out_size; (void)ws_size;
    const float* embed       = (const float*)d_in[0];
    const float* action      = (const float*)d_in[1];
    const float* noise_prior = (const float*)d_in[2];
    const float* noise_post  = (const float*)d_in[3];
    const float* Wi   = (const float*)d_in[4];
    const float* bi   = (const float*)d_in[5];
    const float* W_ih = (const float*)d_in[6];
    const float* W_hh = (const float*)d_in[7];
    const float* b_ih = (const float*)d_in[8];
    const float* b_hh = (const float*)d_in[9];
    const float* Wp1  = (const float*)d_in[10];
    const float* bp1  = (const float*)d_in[11];
    const float* Wp2  = (const float*)d_in[12];
    const float* bp2  = (const float*)d_in[13];
    const float* Wq1  = (const float*)d_in[14];
    const float* bq1  = (const float*)d_in[15];
    const float* Wq2  = (const float*)d_in[16];
    const float* bq2  = (const float*)d_in[17];
    float* out = (float*)d_out;
    u16* wp = (u16*)d_ws;

    hipLaunchKernelGGL(prep_pack, dim3((P_TOTAL + 255) / 256), dim3(256), 0, stream,
                       Wi, W_ih, W_hh, Wq1, Wq2, Wp1, Wp2, wp);
    hipLaunchKernelGGL(epre_mfma, dim3(256), dim3(512), 0, stream,
                       embed, wp, bq1, out);
    hipLaunchKernelGGL(scan_mfma, dim3(64), dim3(512), 0, stream,
                       action, noise_post, b_ih, b_hh, bi, bq2, wp, out);
    hipLaunchKernelGGL(prior_mfma, dim3(1024), dim3(256), 0, stream,
                       noise_prior, wp, bp1, bp2, out);
}

// Round 6
// 2670.411 us; speedup vs baseline: 1.3526x; 1.3526x over previous
//
#include <hip/hip_runtime.h>
#include <math.h>

typedef unsigned short u16;
typedef unsigned int   u32;
typedef __attribute__((ext_vector_type(8))) short short8;
typedef __attribute__((ext_vector_type(4))) float f32x4;

#define NT 64
#define OC 580

// packed bf16 weight fragments (512 u16 each) in d_ws (u16 units)
#define P_WI    0                       // frag = tt*2+ks          (26)
#define P_WIH   13312                   // frag = (g*13+tt)*7+ks   (273)
#define P_WHH   153088                  // frag = (g*13+tt)*7+ks   (273)
#define P_WQ1   292864                  // frag = tt*7+ks          (91)
#define P_WQ2   339456                  // frag = tt*7+ks          (28)
#define P_EB    353792                  // frag = ks*13+tt, ks<32  (416)
#define P_WP1   566784                  // frag = ks*13+tt         (91)
#define P_WP2   613376                  // frag = ks*4+tt          (28)
#define P_TOTAL 627712                  // 1.26 MB

__device__ __forceinline__ float elu_f(float x) { return x > 0.f ? x : __expf(x) - 1.f; }
__device__ __forceinline__ float sig_f(float x) { return 1.f / (1.f + __expf(-x)); }
__device__ __forceinline__ float sp_f(float x)  { return x > 20.f ? x : log1pf(__expf(x)); }

__device__ __forceinline__ u16 f2b(float f) {   // f32 -> bf16 RNE
    union { float f; u32 u; } v; v.f = f;
    u32 r = (v.u + 0x7fffu + ((v.u >> 16) & 1u)) >> 16;
    return (u16)r;
}

__device__ __forceinline__ short8 pack8(float4 v0, float4 v1) {
    short8 r;
    r[0] = (short)f2b(v0.x); r[1] = (short)f2b(v0.y);
    r[2] = (short)f2b(v0.z); r[3] = (short)f2b(v0.w);
    r[4] = (short)f2b(v1.x); r[5] = (short)f2b(v1.y);
    r[6] = (short)f2b(v1.z); r[7] = (short)f2b(v1.w);
    return r;
}

#define MFMA(a, b, c) __builtin_amdgcn_mfma_f32_16x16x32_bf16((a), (b), (c), 0, 0, 0)

// ---------------------------------------------------------------------------
// prep: pack all weights to bf16 MFMA B-fragments (512 u16 each):
// frag[ln][e] = W[n0+(ln&15)][k0+(ln>>4)*8+e], zero-padded.
// ---------------------------------------------------------------------------
__global__ __launch_bounds__(256) void prep_pack(
    const float* __restrict__ Wi, const float* __restrict__ W_ih,
    const float* __restrict__ W_hh, const float* __restrict__ Wq1,
    const float* __restrict__ Wq2, const float* __restrict__ Wp1,
    const float* __restrict__ Wp2, u16* __restrict__ wp)
{
    for (size_t r = (size_t)blockIdx.x * 256 + threadIdx.x; r < P_TOTAL;
         r += (size_t)gridDim.x * 256) {
        float val = 0.f;
        const int ln = (int)((r >> 3) & 63), e = (int)(r & 7);
        const int row = ln & 15, kg = ln >> 4;
        if (r < P_WIH) {                            // Wi [200 x 36]
            int frag = (int)(r >> 9);
            int tt = frag >> 1, ks = frag & 1;
            int j = tt * 16 + row, k = ks * 32 + kg * 8 + e;
            if (j < 200 && k < 36) val = Wi[j * 36 + k];
        } else if (r < P_WHH) {                     // W_ih [600 x 200]
            int frag = (int)((r - P_WIH) >> 9);
            int u = frag / 7, ks = frag % 7;
            int g = u / 13, tt = u % 13;
            int j = tt * 16 + row, k = ks * 32 + kg * 8 + e;
            if (j < 200 && k < 200) val = W_ih[(size_t)(g * 200 + j) * 200 + k];
        } else if (r < P_WQ1) {                     // W_hh [600 x 200]
            int frag = (int)((r - P_WHH) >> 9);
            int u = frag / 7, ks = frag % 7;
            int g = u / 13, tt = u % 13;
            int j = tt * 16 + row, k = ks * 32 + kg * 8 + e;
            if (j < 200 && k < 200) val = W_hh[(size_t)(g * 200 + j) * 200 + k];
        } else if (r < P_WQ2) {                     // Wq1[:, :200]
            int frag = (int)((r - P_WQ1) >> 9);
            int tt = frag / 7, ks = frag % 7;
            int j = tt * 16 + row, k = ks * 32 + kg * 8 + e;
            if (j < 200 && k < 200) val = Wq1[(size_t)j * 1224 + k];
        } else if (r < P_EB) {                      // Wq2 [60 x 200]
            int frag = (int)((r - P_WQ2) >> 9);
            int tt = frag / 7, ks = frag % 7;
            int j = tt * 16 + row, k = ks * 32 + kg * 8 + e;
            if (j < 60 && k < 200) val = Wq2[(size_t)j * 200 + k];
        } else if (r < P_WP1) {                     // Wq1[:, 200:1224]
            int frag = (int)((r - P_EB) >> 9);
            int ks = frag / 13, tt = frag % 13;
            int j = tt * 16 + row, k = ks * 32 + kg * 8 + e;
            if (j < 200) val = Wq1[(size_t)j * 1224 + 200 + k];
        } else if (r < P_WP2) {                     // Wp1 [200 x 200]
            int frag = (int)((r - P_WP1) >> 9);
            int ks = frag / 13, tt = frag % 13;
            int j = tt * 16 + row, k = ks * 32 + kg * 8 + e;
            if (j < 200 && k < 200) val = Wp1[(size_t)j * 200 + k];
        } else {                                    // Wp2 [60 x 200]
            int frag = (int)((r - P_WP2) >> 9);
            int ks = frag / 4, tt = frag % 4;
            int j = tt * 16 + row, k = ks * 32 + kg * 8 + e;
            if (j < 60 && k < 200) val = Wp2[(size_t)j * 200 + k];
        }
        wp[r] = f2b(val);
    }
}

// ---------------------------------------------------------------------------
// Epre (MFMA): out[bt*580+290+j] = embed[bt] . Wq1[j][200:] + bq1[j]
// ---------------------------------------------------------------------------
__global__ __launch_bounds__(512) void epre_mfma(
    const float* __restrict__ embed, const u16* __restrict__ wp,
    const float* __restrict__ bq1, float* __restrict__ out)
{
    const int tid = threadIdx.x;
    const int wv = tid >> 6, ln = tid & 63;
    const int arow = ln & 15, kgrp = ln >> 4;
    const int m0 = blockIdx.x * 256 + wv * 32;

    f32x4 acc[2][13];
    #pragma unroll
    for (int tt = 0; tt < 13; ++tt) {
        const int j = tt * 16 + arow;
        const float bv = (j < 200) ? bq1[j] : 0.f;
        acc[0][tt] = (f32x4){bv, bv, bv, bv};
        acc[1][tt] = acc[0][tt];
    }
    const float* e0 = &embed[(size_t)(m0 + arow) * 1024 + kgrp * 8];
    const float* e1 = e0 + (size_t)16 * 1024;

    for (int ks = 0; ks < 32; ++ks) {
        short8 a0, a1;
        {
            float4 v0 = *(const float4*)(e0 + ks * 32);
            float4 v1 = *(const float4*)(e0 + ks * 32 + 4);
            a0 = pack8(v0, v1);
            float4 w0 = *(const float4*)(e1 + ks * 32);
            float4 w1 = *(const float4*)(e1 + ks * 32 + 4);
            a1 = pack8(w0, w1);
        }
        const u16* bp = &wp[P_EB + (size_t)ks * 13 * 512 + (size_t)ln * 8];
        #pragma unroll
        for (int tt = 0; tt < 13; ++tt) {
            short8 b = *(const short8*)(bp + (size_t)tt * 512);
            acc[0][tt] = MFMA(a0, b, acc[0][tt]);
            acc[1][tt] = MFMA(a1, b, acc[1][tt]);
        }
    }
    #pragma unroll
    for (int f = 0; f < 2; ++f) {
        const size_t rbase = (size_t)(m0 + f * 16 + kgrp * 4);
        #pragma unroll
        for (int tt = 0; tt < 13; ++tt) {
            const int j = tt * 16 + arow;
            if (j < 200) {
                #pragma unroll
                for (int e = 0; e < 4; ++e)
                    out[(rbase + e) * OC + 290 + j] = acc[f][tt][e];
            }
        }
    }
}

// ---------------------------------------------------------------------------
// Scan: 64 blocks x 16 rows x 512 thr (8 waves), round-3 structure +
// 256 VGPR + explicit register prefetch of weight fragments (L2-resident).
// ---------------------------------------------------------------------------
__global__ __launch_bounds__(512, 1) void scan_mfma(
    const float* __restrict__ action, const float* __restrict__ noise_post,
    const float* __restrict__ b_ih, const float* __restrict__ b_hh,
    const float* __restrict__ bi, const float* __restrict__ bq2,
    const u16* __restrict__ wp, float* __restrict__ out)
{
    __shared__ __align__(16) u16   s_in0[16][64];
    __shared__ __align__(16) u16   s_x[16][232];
    __shared__ __align__(16) u16   s_db[2][16][232];
    __shared__ __align__(16) u16   s_hq[16][232];
    __shared__ __align__(16) float s_dfT[208][20];   // deter f32 carry, transposed
    __shared__ __align__(16) float s_epT[208][20];   // Epre staged, transposed
    __shared__ __align__(16) float s_q[16][64];

    const int tid  = threadIdx.x;
    const int wv   = tid >> 6, ln = tid & 63;
    const int arow = ln & 15, kgrp = ln >> 4;
    const int b0   = blockIdx.x * 16;

    const int t0 = wv, t1 = wv + 8;
    const bool has2 = (t1 < 13);
    const int j0 = t0 * 16 + arow;
    const int j1 = t1 * 16 + arow;
    float bih0[3], bhh0[3], bih1[3], bhh1[3];
    #pragma unroll
    for (int g = 0; g < 3; ++g) {
        bih0[g] = b_ih[g * 200 + j0];
        bhh0[g] = b_hh[g * 200 + j0];
        bih1[g] = (has2 && j1 < 200) ? b_ih[g * 200 + j1] : 0.f;
        bhh1[g] = (has2 && j1 < 200) ? b_hh[g * 200 + j1] : 0.f;
    }
    const float biA0 = bi[j0];
    const float biA1 = (has2 && j1 < 200) ? bi[j1] : 0.f;
    const float bD   = (wv < 4 && (wv * 16 + arow) < 60) ? bq2[wv * 16 + arow] : 0.f;

    // ---- zero-init LDS ----
    { u32* z = (u32*)s_in0; for (int i = tid; i < 16 * 64 / 2; i += 512) z[i] = 0; }
    { u32* z = (u32*)s_x;   for (int i = tid; i < 16 * 232 / 2; i += 512) z[i] = 0; }
    { u32* z = (u32*)s_db;  for (int i = tid; i < 2 * 16 * 232 / 2; i += 512) z[i] = 0; }
    { u32* z = (u32*)s_hq;  for (int i = tid; i < 16 * 232 / 2; i += 512) z[i] = 0; }
    { float* z = (float*)s_dfT; for (int i = tid; i < 208 * 20; i += 512) z[i] = 0.f; }
    { float* z = (float*)s_epT; for (int i = tid; i < 208 * 20; i += 512) z[i] = 0.f; }
    __syncthreads();

    // ---- prologue: stage Epre(0) + action(0) ----
    for (int idx = tid; idx < 16 * 200; idx += 512) {
        int i = idx / 200, j = idx - i * 200;
        s_epT[j][i] = out[((size_t)(b0 + i) * NT + 0) * OC + 290 + j];
    }
    if (tid < 96) {
        int i = tid / 6, c = tid - i * 6;
        s_in0[i][30 + c] = f2b(action[((size_t)(b0 + i) * NT + 0) * 6 + c]);
    }
    __syncthreads();

    int cur = 0;
    for (int t = 0; t < NT; ++t) {
        // ======== phase A: x = elu([stoch|act] @ Wi^T + bi) ========
        {
            short8 w00 = *(const short8*)&wp[P_WI + (size_t)(t0 * 2 + 0) * 512 + ln * 8];
            short8 w01 = *(const short8*)&wp[P_WI + (size_t)(t0 * 2 + 1) * 512 + ln * 8];
            short8 w10, w11;
            if (has2) {
                w10 = *(const short8*)&wp[P_WI + (size_t)(t1 * 2 + 0) * 512 + ln * 8];
                w11 = *(const short8*)&wp[P_WI + (size_t)(t1 * 2 + 1) * 512 + ln * 8];
            }
            short8 af0 = *(const short8*)&s_in0[arow][kgrp * 8];
            short8 af1 = *(const short8*)&s_in0[arow][32 + kgrp * 8];
            f32x4 a0 = {biA0, biA0, biA0, biA0};
            a0 = MFMA(af0, w00, a0);
            a0 = MFMA(af1, w01, a0);
            #pragma unroll
            for (int e = 0; e < 4; ++e)
                s_x[kgrp * 4 + e][j0] = f2b(elu_f(a0[e]));
            if (has2) {
                f32x4 a1 = {biA1, biA1, biA1, biA1};
                a1 = MFMA(af0, w10, a1);
                a1 = MFMA(af1, w11, a1);
                #pragma unroll
                for (int e = 0; e < 4; ++e)
                    s_x[kgrp * 4 + e][j1] = f2b(elu_f(a1[e]));
            }
        }
        __syncthreads();

        // ======== phase B: GRU gates (depth-1 frag prefetch) + combine ========
        {
            f32x4 gi0[3], gh0[3], gi1[3], gh1[3];
            #pragma unroll
            for (int g = 0; g < 3; ++g) {
                gi0[g] = (f32x4){bih0[g], bih0[g], bih0[g], bih0[g]};
                gh0[g] = (f32x4){bhh0[g], bhh0[g], bhh0[g], bhh0[g]};
                gi1[g] = (f32x4){bih1[g], bih1[g], bih1[g], bih1[g]};
                gh1[g] = (f32x4){bhh1[g], bhh1[g], bhh1[g], bhh1[g]};
            }
#define LDF(base, g, tt, ks) \
    (*(const short8*)&wp[(base) + ((size_t)((g) * 13 + (tt)) * 7 + (ks)) * 512 + ln * 8])
            short8 fi[2][3][2], fh[2][3][2];
            #pragma unroll
            for (int g = 0; g < 3; ++g) {
                fi[0][g][0] = LDF(P_WIH, g, t0, 0);
                fh[0][g][0] = LDF(P_WHH, g, t0, 0);
                if (has2) {
                    fi[0][g][1] = LDF(P_WIH, g, t1, 0);
                    fh[0][g][1] = LDF(P_WHH, g, t1, 0);
                }
            }
            #pragma unroll
            for (int ks = 0; ks < 7; ++ks) {
                const int p = ks & 1;
                if (ks < 6) {   // prefetch next ks into other parity
                    #pragma unroll
                    for (int g = 0; g < 3; ++g) {
                        fi[p ^ 1][g][0] = LDF(P_WIH, g, t0, ks + 1);
                        fh[p ^ 1][g][0] = LDF(P_WHH, g, t0, ks + 1);
                        if (has2) {
                            fi[p ^ 1][g][1] = LDF(P_WIH, g, t1, ks + 1);
                            fh[p ^ 1][g][1] = LDF(P_WHH, g, t1, ks + 1);
                        }
                    }
                }
                short8 ax = *(const short8*)&s_x[arow][ks * 32 + kgrp * 8];
                short8 ad = *(const short8*)&s_db[cur][arow][ks * 32 + kgrp * 8];
                #pragma unroll
                for (int g = 0; g < 3; ++g) {
                    gi0[g] = MFMA(ax, fi[p][g][0], gi0[g]);
                    gh0[g] = MFMA(ad, fh[p][g][0], gh0[g]);
                }
                if (has2) {
                    #pragma unroll
                    for (int g = 0; g < 3; ++g) {
                        gi1[g] = MFMA(ax, fi[p][g][1], gi1[g]);
                        gh1[g] = MFMA(ad, fh[p][g][1], gh1[g]);
                    }
                }
            }
#undef LDF
            // prefetch phase-C fragments (land during combine VALU work)
            short8 fc0[7], fc1[7];
            #pragma unroll
            for (int ks = 0; ks < 7; ++ks) {
                fc0[ks] = *(const short8*)&wp[P_WQ1 + (size_t)(t0 * 7 + ks) * 512 + ln * 8];
                if (has2)
                    fc1[ks] = *(const short8*)&wp[P_WQ1 + (size_t)(t1 * 7 + ks) * 512 + ln * 8];
            }
            {   // combine tile 0
                float4 dp = *(const float4*)&s_dfT[j0][kgrp * 4];
                float dn[4];
                const float dpv[4] = {dp.x, dp.y, dp.z, dp.w};
                #pragma unroll
                for (int e = 0; e < 4; ++e) {
                    float rr = sig_f(gi0[0][e] + gh0[0][e]);
                    float zz = sig_f(gi0[1][e] + gh0[1][e]);
                    float nn = tanhf(gi0[2][e] + rr * gh0[2][e]);
                    dn[e] = (1.f - zz) * nn + zz * dpv[e];
                }
                float4 dnv; dnv.x = dn[0]; dnv.y = dn[1]; dnv.z = dn[2]; dnv.w = dn[3];
                *(float4*)&s_dfT[j0][kgrp * 4] = dnv;
                #pragma unroll
                for (int e = 0; e < 4; ++e) s_db[cur ^ 1][kgrp * 4 + e][j0] = f2b(dn[e]);
            }
            if (has2) {   // combine tile 1
                float4 dp = *(const float4*)&s_dfT[j1][kgrp * 4];
                float dn[4];
                const float dpv[4] = {dp.x, dp.y, dp.z, dp.w};
                #pragma unroll
                for (int e = 0; e < 4; ++e) {
                    float rr = sig_f(gi1[0][e] + gh1[0][e]);
                    float zz = sig_f(gi1[1][e] + gh1[1][e]);
                    float nn = tanhf(gi1[2][e] + rr * gh1[2][e]);
                    dn[e] = (1.f - zz) * nn + zz * dpv[e];
                }
                float4 dnv; dnv.x = dn[0]; dnv.y = dn[1]; dnv.z = dn[2]; dnv.w = dn[3];
                *(float4*)&s_dfT[j1][kgrp * 4] = dnv;
                #pragma unroll
                for (int e = 0; e < 4; ++e) s_db[cur ^ 1][kgrp * 4 + e][j1] = f2b(dn[e]);
            }
            __syncthreads();

            // ======== phase C: hq = elu(deter_new @ Wq1a^T + Epre) ========
            // prefetch phase-D fragments (waves 0-3)
            short8 fd[7];
            if (wv < 4) {
                #pragma unroll
                for (int ks = 0; ks < 7; ++ks)
                    fd[ks] = *(const short8*)&wp[P_WQ2 + (size_t)(wv * 7 + ks) * 512 + ln * 8];
            }
            {
                float4 ep0 = *(const float4*)&s_epT[j0][kgrp * 4];
                f32x4 accC0 = {ep0.x, ep0.y, ep0.z, ep0.w};
                f32x4 accC1 = {0.f, 0.f, 0.f, 0.f};
                if (has2) {
                    float4 ep1 = *(const float4*)&s_epT[j1][kgrp * 4];
                    accC1 = (f32x4){ep1.x, ep1.y, ep1.z, ep1.w};
                }
                #pragma unroll
                for (int ks = 0; ks < 7; ++ks) {
                    short8 adn = *(const short8*)&s_db[cur ^ 1][arow][ks * 32 + kgrp * 8];
                    accC0 = MFMA(adn, fc0[ks], accC0);
                    if (has2) accC1 = MFMA(adn, fc1[ks], accC1);
                }
                #pragma unroll
                for (int e = 0; e < 4; ++e)
                    s_hq[kgrp * 4 + e][j0] = f2b(elu_f(accC0[e]));
                if (has2) {
                    #pragma unroll
                    for (int e = 0; e < 4; ++e)
                        s_hq[kgrp * 4 + e][j1] = f2b(elu_f(accC1[e]));
                }
            }
            __syncthreads();

            // ======== phase D1: q = hq @ Wq2^T + bq2 ========
            if (wv < 4) {
                f32x4 aq = {bD, bD, bD, bD};
                #pragma unroll
                for (int ks = 0; ks < 7; ++ks) {
                    short8 ah = *(const short8*)&s_hq[arow][ks * 32 + kgrp * 8];
                    aq = MFMA(ah, fd[ks], aq);
                }
                #pragma unroll
                for (int e = 0; e < 4; ++e) s_q[kgrp * 4 + e][wv * 16 + arow] = aq[e];
            }
            __syncthreads();
        }

        // ======== D2: sample + global writes + stage t+1 ========
        {
            if (tid < 480) {
                int i = tid / 30, ss = tid - i * 30;
                float qm = s_q[i][ss];
                float qs = sp_f(s_q[i][30 + ss]) + 0.1f;
                size_t bt = (size_t)(b0 + i) * NT + t;
                float qst = noise_post[bt * 30 + ss] * qs + qm;
                size_t o = bt * OC;
                out[o + ss]      = qm;
                out[o + 30 + ss] = qs;
                out[o + 60 + ss] = qst;
                s_in0[i][ss] = f2b(qst);
            }
            for (int idx = tid; idx < 16 * 200; idx += 512) {
                int i = idx / 200, j = idx - i * 200;
                float d = s_dfT[j][i];
                size_t o = ((size_t)(b0 + i) * NT + t) * OC;
                out[o + 90 + j]  = d;
                out[o + 380 + j] = d;
            }
            if (t + 1 < NT) {
                for (int idx = tid; idx < 16 * 200; idx += 512) {
                    int i = idx / 200, j = idx - i * 200;
                    s_epT[j][i] = out[((size_t)(b0 + i) * NT + (t + 1)) * OC + 290 + j];
                }
                if (tid < 96) {
                    int i = tid / 6, c = tid - i * 6;
                    s_in0[i][30 + c] = f2b(action[((size_t)(b0 + i) * NT + (t + 1)) * 6 + c]);
                }
            }
            __syncthreads();
        }
        cur ^= 1;
    }
}

// ---------------------------------------------------------------------------
// Prior head (MFMA): 1024 blocks x 64 bt-rows, 256 thr (4 waves x 16 rows).
// ---------------------------------------------------------------------------
__global__ __launch_bounds__(256) void prior_mfma(
    const float* __restrict__ noise_prior, const u16* __restrict__ wp,
    const float* __restrict__ bp1, const float* __restrict__ bp2,
    float* __restrict__ out)
{
    __shared__ __align__(16) u16   s_hp[64][232];
    __shared__ __align__(16) float s_p[64][68];
    const int tid = threadIdx.x;
    const int wv = tid >> 6, ln = tid & 63;
    const int arow = ln & 15, kgrp = ln >> 4;
    const size_t bt0 = (size_t)blockIdx.x * 64;
    const int m0 = wv * 16;

    for (int idx = tid; idx < 64 * 32; idx += 256) {   // zero pad cols 200..231
        int r2 = idx >> 5, c = 200 + (idx & 31);
        s_hp[r2][c] = 0;
    }

    // GEMM1: hp = elu(deter @ Wp1^T + bp1)
    f32x4 acc[13];
    #pragma unroll
    for (int tt = 0; tt < 13; ++tt) {
        const int j = tt * 16 + arow;
        const float bv = (j < 200) ? bp1[j] : 0.f;
        acc[tt] = (f32x4){bv, bv, bv, bv};
    }
    for (int ks = 0; ks < 7; ++ks) {
        short8 a;
        const int k0 = ks * 32 + kgrp * 8;
        if (k0 <= 192) {
            const float* dp = &out[(bt0 + m0 + arow) * OC + 380 + k0];
            float4 v0 = *(const float4*)dp;
            float4 v1 = *(const float4*)(dp + 4);
            a = pack8(v0, v1);
        } else {
            a = (short8){0, 0, 0, 0, 0, 0, 0, 0};
        }
        const u16* bp = &wp[P_WP1 + (size_t)ks * 13 * 512 + (size_t)ln * 8];
        #pragma unroll
        for (int tt = 0; tt < 13; ++tt)
            acc[tt] = MFMA(a, *(const short8*)(bp + (size_t)tt * 512), acc[tt]);
    }
    #pragma unroll
    for (int tt = 0; tt < 13; ++tt)
        #pragma unroll
        for (int e = 0; e < 4; ++e)
            s_hp[m0 + kgrp * 4 + e][tt * 16 + arow] = f2b(elu_f(acc[tt][e]));
    __syncthreads();

    // GEMM2: p = hp @ Wp2^T + bp2
    f32x4 acc2[4];
    #pragma unroll
    for (int tt = 0; tt < 4; ++tt) {
        const int j = tt * 16 + arow;
        const float bv = (j < 60) ? bp2[j] : 0.f;
        acc2[tt] = (f32x4){bv, bv, bv, bv};
    }
    #pragma unroll
    for (int ks = 0; ks < 7; ++ks) {
        short8 ah = *(const short8*)&s_hp[m0 + arow][ks * 32 + kgrp * 8];
        const u16* bp = &wp[P_WP2 + (size_t)ks * 4 * 512 + (size_t)ln * 8];
        #pragma unroll
        for (int tt = 0; tt < 4; ++tt)
            acc2[tt] = MFMA(ah, *(const short8*)(bp + (size_t)tt * 512), acc2[tt]);
    }
    #pragma unroll
    for (int tt = 0; tt < 4; ++tt)
        #pragma unroll
        for (int e = 0; e < 4; ++e)
            s_p[m0 + kgrp * 4 + e][tt * 16 + arow] = acc2[tt][e];
    __syncthreads();

    for (int idx = tid; idx < 64 * 30; idx += 256) {
        int i = idx / 30, ss = idx - i * 30;
        float pm = s_p[i][ss];
        float ps = sp_f(s_p[i][30 + ss]) + 0.1f;
        float pst = noise_prior[(bt0 + i) * 30 + ss] * ps + pm;
        size_t base = (bt0 + i) * OC;
        out[base + 290 + ss] = pm;
        out[base + 320 + ss] = ps;
        out[base + 350 + ss] = pst;
    }
}

extern "C" void kernel_launch(void* const* d_in, const int* in_sizes, int n_in,
                              void* d_out, int out_size, void* d_ws, size_t ws_size,
                              hipStream_t stream)
{
    (void)in_sizes; (void)n_in; (void)out_size; (void)ws_size;
    const float* embed       = (const float*)d_in[0];
    const float* action      = (const float*)d_in[1];
    const float* noise_prior = (const float*)d_in[2];
    const float* noise_post  = (const float*)d_in[3];
    const float* Wi   = (const float*)d_in[4];
    const float* bi   = (const float*)d_in[5];
    const float* W_ih = (const float*)d_in[6];
    const float* W_hh = (const float*)d_in[7];
    const float* b_ih = (const float*)d_in[8];
    const float* b_hh = (const float*)d_in[9];
    const float* Wp1  = (const float*)d_in[10];
    const float* bp1  = (const float*)d_in[11];
    const float* Wp2  = (const float*)d_in[12];
    const float* bp2  = (const float*)d_in[13];
    const float* Wq1  = (const float*)d_in[14];
    const float* bq1  = (const float*)d_in[15];
    const float* Wq2  = (const float*)d_in[16];
    const float* bq2  = (const float*)d_in[17];
    float* out = (float*)d_out;
    u16* wp = (u16*)d_ws;

    hipLaunchKernelGGL(prep_pack, dim3((P_TOTAL + 255) / 256), dim3(256), 0, stream,
                       Wi, W_ih, W_hh, Wq1, Wq2, Wp1, Wp2, wp);
    hipLaunchKernelGGL(epre_mfma, dim3(256), dim3(512), 0, stream,
                       embed, wp, bq1, out);
    hipLaunchKernelGGL(scan_mfma, dim3(64), dim3(512), 0, stream,
                       action, noise_post, b_ih, b_hh, bi, bq2, wp, out);
    hipLaunchKernelGGL(prior_mfma, dim3(1024), dim3(256), 0, stream,
                       noise_prior, wp, bp1, bp2, out);
}

// Round 7
// 2028.603 us; speedup vs baseline: 1.7805x; 1.3164x over previous
//
#include <hip/hip_runtime.h>
#include <math.h>

typedef unsigned short u16;
typedef unsigned int   u32;
typedef __attribute__((ext_vector_type(8))) short short8;
typedef __attribute__((ext_vector_type(4))) float f32x4;

#define NT 64
#define OC 580

// packed bf16 weight fragments (1024-u16 spacing, 512 used) in d_ws (u16 units)
// -- identical layout to round 3 (proven FETCH ~49MB, L2-resident) --
#define P_WI    0        // [tt13][ks2]
#define P_WIH   26624    // [(g*13+tt)][ks7]
#define P_WHH   306176
#define P_WQ1   585728   // [tt13][ks7]
#define P_WQ2   678912   // [tt4][ks7]
#define P_EB    707584   // [ks32][tt13]
#define P_WP1   1133568  // [ks7][tt13]
#define P_WP2   1226752  // [ks7][tt4]
#define P_TOTAL 1255424

__device__ __forceinline__ float elu_f(float x) { return x > 0.f ? x : __expf(x) - 1.f; }
__device__ __forceinline__ float sig_f(float x) { return 1.f / (1.f + __expf(-x)); }
__device__ __forceinline__ float sp_f(float x)  { return x > 20.f ? x : log1pf(__expf(x)); }

__device__ __forceinline__ u16 f2b(float f) {   // f32 -> bf16 RNE
    union { float f; u32 u; } v; v.f = f;
    u32 r = (v.u + 0x7fffu + ((v.u >> 16) & 1u)) >> 16;
    return (u16)r;
}

__device__ __forceinline__ short8 pack8(float4 v0, float4 v1) {
    short8 r;
    r[0] = (short)f2b(v0.x); r[1] = (short)f2b(v0.y);
    r[2] = (short)f2b(v0.z); r[3] = (short)f2b(v0.w);
    r[4] = (short)f2b(v1.x); r[5] = (short)f2b(v1.y);
    r[6] = (short)f2b(v1.z); r[7] = (short)f2b(v1.w);
    return r;
}

#define MFMA(a, b, c) __builtin_amdgcn_mfma_f32_16x16x32_bf16((a), (b), (c), 0, 0, 0)

// ---------------------------------------------------------------------------
// prep: pack weights to bf16 MFMA B-fragment order (round-3 layout):
// frag[lane][e] = W[n0 + (lane&15)][k0 + (lane>>4)*8 + e]  (0-padded)
// ---------------------------------------------------------------------------
__global__ __launch_bounds__(256) void prep_pack(
    const float* __restrict__ Wi, const float* __restrict__ W_ih,
    const float* __restrict__ W_hh, const float* __restrict__ Wq1,
    const float* __restrict__ Wq2, const float* __restrict__ Wp1,
    const float* __restrict__ Wp2, u16* __restrict__ wp)
{
    for (size_t r = (size_t)blockIdx.x * 256 + threadIdx.x; r < P_TOTAL;
         r += (size_t)gridDim.x * 256) {
        float val = 0.f;
        if (r < P_WIH) {                           // Wi: [200 x 36]
            int tile = r / 1024, lane = (r % 1024) / 8, el = r % 8;
            int tt = tile / 2, ks = tile % 2;
            int j = tt * 16 + (lane & 15), k = ks * 32 + (lane >> 4) * 8 + el;
            if (j < 200 && k < 36 && lane < 64) val = Wi[j * 36 + k];
        } else if (r < P_WHH) {                    // W_ih
            size_t q = r - P_WIH;
            int tile = q / 1024, lane = (q % 1024) / 8, el = q % 8;
            int g = tile / 91, rem = tile % 91, tt = rem / 7, ks = rem % 7;
            int j = tt * 16 + (lane & 15), k = ks * 32 + (lane >> 4) * 8 + el;
            if (j < 200 && k < 200 && lane < 64) val = W_ih[(size_t)(g * 200 + j) * 200 + k];
        } else if (r < P_WQ1) {                    // W_hh
            size_t q = r - P_WHH;
            int tile = q / 1024, lane = (q % 1024) / 8, el = q % 8;
            int g = tile / 91, rem = tile % 91, tt = rem / 7, ks = rem % 7;
            int j = tt * 16 + (lane & 15), k = ks * 32 + (lane >> 4) * 8 + el;
            if (j < 200 && k < 200 && lane < 64) val = W_hh[(size_t)(g * 200 + j) * 200 + k];
        } else if (r < P_WQ2) {                    // Wq1[:, :200]
            size_t q = r - P_WQ1;
            int tile = q / 1024, lane = (q % 1024) / 8, el = q % 8;
            int tt = tile / 7, ks = tile % 7;
            int j = tt * 16 + (lane & 15), k = ks * 32 + (lane >> 4) * 8 + el;
            if (j < 200 && k < 200 && lane < 64) val = Wq1[(size_t)j * 1224 + k];
        } else if (r < P_EB) {                     // Wq2: [60 x 200]
            size_t q = r - P_WQ2;
            int tile = q / 1024, lane = (q % 1024) / 8, el = q % 8;
            int tt = tile / 7, ks = tile % 7;
            int j = tt * 16 + (lane & 15), k = ks * 32 + (lane >> 4) * 8 + el;
            if (j < 60 && k < 200 && lane < 64) val = Wq2[(size_t)j * 200 + k];
        } else if (r < P_WP1) {                    // epre B: Wq1[:,200:1224]
            size_t q = r - P_EB;
            int tile = q / 1024, lane = (q % 1024) / 8, el = q % 8;
            int ks = tile / 13, tt = tile % 13;
            int j = tt * 16 + (lane & 15), k = ks * 32 + (lane >> 4) * 8 + el;
            if (j < 200 && lane < 64) val = Wq1[(size_t)j * 1224 + 200 + k];
        } else if (r < P_WP2) {                    // Wp1: [200 x 200]
            size_t q = r - P_WP1;
            int tile = q / 1024, lane = (q % 1024) / 8, el = q % 8;
            int ks = tile / 13, tt = tile % 13;
            int j = tt * 16 + (lane & 15), k = ks * 32 + (lane >> 4) * 8 + el;
            if (j < 200 && k < 200 && lane < 64) val = Wp1[(size_t)j * 200 + k];
        } else {                                   // Wp2: [60 x 200]
            size_t q = r - P_WP2;
            int tile = q / 1024, lane = (q % 1024) / 8, el = q % 8;
            int ks = tile / 4, tt = tile % 4;
            int j = tt * 16 + (lane & 15), k = ks * 32 + (lane >> 4) * 8 + el;
            if (j < 60 && k < 200 && lane < 64) val = Wp2[(size_t)j * 200 + k];
        }
        wp[r] = f2b(val);
    }
}

// ---------------------------------------------------------------------------
// Epre (MFMA): out[bt*580+290+j] = embed[bt] . Wq1[j][200:] + bq1[j]
// (round-3 version, verbatim)
// ---------------------------------------------------------------------------
__global__ __launch_bounds__(512) void epre_mfma(
    const float* __restrict__ embed, const u16* __restrict__ wp,
    const float* __restrict__ bq1, float* __restrict__ out)
{
    const int tid = threadIdx.x;
    const int wv = tid >> 6, ln = tid & 63;
    const int arow = ln & 15, kgrp = ln >> 4;
    const int m0 = blockIdx.x * 256 + wv * 32;

    f32x4 acc[2][13];
    #pragma unroll
    for (int tt = 0; tt < 13; ++tt) {
        const int j = tt * 16 + arow;
        const float bv = (j < 200) ? bq1[j] : 0.f;
        acc[0][tt] = (f32x4){bv, bv, bv, bv};
        acc[1][tt] = acc[0][tt];
    }
    const float* e0 = &embed[(size_t)(m0 + arow) * 1024 + kgrp * 8];
    const float* e1 = e0 + (size_t)16 * 1024;

    for (int ks = 0; ks < 32; ++ks) {
        short8 a0, a1;
        {
            float4 v0 = *(const float4*)(e0 + ks * 32);
            float4 v1 = *(const float4*)(e0 + ks * 32 + 4);
            a0 = pack8(v0, v1);
            float4 w0 = *(const float4*)(e1 + ks * 32);
            float4 w1 = *(const float4*)(e1 + ks * 32 + 4);
            a1 = pack8(w0, w1);
        }
        const u16* bp = &wp[P_EB + (size_t)ks * 13 * 1024 + (size_t)ln * 8];
        #pragma unroll
        for (int tt = 0; tt < 13; ++tt) {
            short8 b = *(const short8*)(bp + (size_t)tt * 1024);
            acc[0][tt] = MFMA(a0, b, acc[0][tt]);
            acc[1][tt] = MFMA(a1, b, acc[1][tt]);
        }
    }
    #pragma unroll
    for (int f = 0; f < 2; ++f) {
        const size_t rbase = (size_t)(m0 + f * 16 + kgrp * 4);
        #pragma unroll
        for (int tt = 0; tt < 13; ++tt) {
            const int j = tt * 16 + arow;
            if (j < 200) {
                #pragma unroll
                for (int e = 0; e < 4; ++e)
                    out[(rbase + e) * OC + 290 + j] = acc[f][tt][e];
            }
        }
    }
}

// ---------------------------------------------------------------------------
// Scan: 64 blocks x 16 rows x 1024 thr (16 waves, 4/SIMD). Round-2-style
// inline L2 fragment loads (proven L2-resident), balanced <=3 units/wave,
// LDS gate arrays, early-issued Epre(t+1)/action(t+1) loads (T14).
// ---------------------------------------------------------------------------
__global__ __launch_bounds__(1024) void scan_mfma(
    const float* __restrict__ action, const float* __restrict__ noise_post,
    const float* __restrict__ b_ih, const float* __restrict__ b_hh,
    const float* __restrict__ bi, const float* __restrict__ bq2,
    const u16* __restrict__ wp, float* __restrict__ out)
{
    __shared__ __align__(16) u16   s_in0[16][64];
    __shared__ __align__(16) u16   s_x[16][232];
    __shared__ __align__(16) u16   s_db[2][16][232];
    __shared__ __align__(16) u16   s_hq[16][232];
    __shared__ __align__(16) float s_r[16][208], s_z[16][208];
    __shared__ __align__(16) float s_inn[16][208], s_hnn[16][208];
    __shared__ __align__(16) float s_df[16][208];
    __shared__ __align__(16) float s_ep[16][208];
    __shared__ __align__(16) float s_q[16][64];

    const int tid  = threadIdx.x;
    const int wv   = tid >> 6, ln = tid & 63;
    const int arow = ln & 15, kgrp = ln >> 4;
    const int b0   = blockIdx.x * 16;

    // phase A/C tile ownership: 1 tile/wave (waves 0-12)
    const bool hasA = (wv < 13);
    const int  tA   = hasA ? wv : 0;
    const int  jA   = tA * 16 + arow;
    const float biA = (hasA && jA < 200) ? bi[jA] : 0.f;

    // phase B unit ownership: units {wv, wv+16, wv+32} < 39
    int  ug[3], uj[3]; bool uv[3]; float bI[3], bH[3];
    size_t baseI[3], baseH[3];
    #pragma unroll
    for (int q = 0; q < 3; ++q) {
        int u = wv + 16 * q;
        uv[q] = (u < 39);
        int ue = uv[q] ? u : 0;
        int g = ue / 13, tt = ue % 13;
        ug[q] = g;
        uj[q] = tt * 16 + arow;
        bI[q] = (uv[q] && uj[q] < 200) ? b_ih[g * 200 + uj[q]] : 0.f;
        bH[q] = (uv[q] && uj[q] < 200) ? b_hh[g * 200 + uj[q]] : 0.f;
        baseI[q] = P_WIH + ((size_t)(g * 13 + tt) * 7) * 1024 + (size_t)ln * 8;
        baseH[q] = P_WHH + ((size_t)(g * 13 + tt) * 7) * 1024 + (size_t)ln * 8;
    }
    const float bD = (wv < 4 && (wv * 16 + arow) < 60) ? bq2[wv * 16 + arow] : 0.f;

    // D2 staging index constants (static, per-thread)
    const int i0 = tid / 200,          j0d = tid - i0 * 200;
    const int i1 = (tid + 1024) / 200, j1d = (tid + 1024) - i1 * 200;
    const int i2 = (tid + 2048) / 200, j2d = (tid + 2048) - i2 * 200;
    const int i3 = (tid + 3072) / 200, j3d = (tid + 3072) - i3 * 200;  // tid<128 only
    const int ia = tid / 6, ca = tid - ia * 6;                          // tid<96 only

    // ---- zero-init LDS ----
    { u32* z = (u32*)s_in0; for (int i = tid; i < 16 * 64 / 2;      i += 1024) z[i] = 0; }
    { u32* z = (u32*)s_x;   for (int i = tid; i < 16 * 232 / 2;     i += 1024) z[i] = 0; }
    { u32* z = (u32*)s_db;  for (int i = tid; i < 2 * 16 * 232 / 2; i += 1024) z[i] = 0; }
    { u32* z = (u32*)s_hq;  for (int i = tid; i < 16 * 232 / 2;     i += 1024) z[i] = 0; }
    { float* z = (float*)s_df; for (int i = tid; i < 16 * 208; i += 1024) z[i] = 0.f; }
    { float* z = (float*)s_ep; for (int i = tid; i < 16 * 208; i += 1024) z[i] = 0.f; }
    __syncthreads();   // zero-init must complete before prologue staging (r4 lesson)

    // ---- prologue: stage Epre(0) + action(0) ----
    for (int idx = tid; idx < 16 * 200; idx += 1024) {
        int i = idx / 200, j = idx - i * 200;
        s_ep[i][j] = out[((size_t)(b0 + i) * NT + 0) * OC + 290 + j];
    }
    if (tid < 96)
        s_in0[ia][30 + ca] = f2b(action[((size_t)(b0 + ia) * NT + 0) * 6 + ca]);
    __syncthreads();

    int cur = 0;
    for (int t = 0; t < NT; ++t) {
        // ======== phase A: x = elu([stoch|act] @ Wi^T + bi) ========
        if (hasA) {
            short8 w0 = *(const short8*)&wp[P_WI + (size_t)(tA * 2 + 0) * 1024 + ln * 8];
            short8 w1 = *(const short8*)&wp[P_WI + (size_t)(tA * 2 + 1) * 1024 + ln * 8];
            short8 a0 = *(const short8*)&s_in0[arow][kgrp * 8];
            short8 a1 = *(const short8*)&s_in0[arow][32 + kgrp * 8];
            f32x4 acc = {biA, biA, biA, biA};
            acc = MFMA(a0, w0, acc);
            acc = MFMA(a1, w1, acc);
            #pragma unroll
            for (int e = 0; e < 4; ++e)
                s_x[kgrp * 4 + e][jA] = f2b(elu_f(acc[e]));
        }
        __syncthreads();

        // ======== phase B: GRU gate GEMMs (inline loads, <=3 units/wave) ========
        {
            f32x4 gi[3], gh[3];
            #pragma unroll
            for (int q = 0; q < 3; ++q) {
                gi[q] = (f32x4){bI[q], bI[q], bI[q], bI[q]};
                gh[q] = (f32x4){bH[q], bH[q], bH[q], bH[q]};
            }
            #pragma unroll
            for (int ks = 0; ks < 7; ++ks) {
                short8 ax = *(const short8*)&s_x[arow][ks * 32 + kgrp * 8];
                short8 ad = *(const short8*)&s_db[cur][arow][ks * 32 + kgrp * 8];
                #pragma unroll
                for (int q = 0; q < 3; ++q) {
                    if (uv[q]) {
                        short8 wih = *(const short8*)&wp[baseI[q] + (size_t)ks * 1024];
                        short8 whh = *(const short8*)&wp[baseH[q] + (size_t)ks * 1024];
                        gi[q] = MFMA(ax, wih, gi[q]);
                        gh[q] = MFMA(ad, whh, gh[q]);
                    }
                }
            }
            #pragma unroll
            for (int q = 0; q < 3; ++q) {
                if (uv[q]) {
                    const int j = uj[q];
                    #pragma unroll
                    for (int e = 0; e < 4; ++e) {
                        const int i = kgrp * 4 + e;
                        if (ug[q] == 0)      s_r[i][j] = sig_f(gi[q][e] + gh[q][e]);
                        else if (ug[q] == 1) s_z[i][j] = sig_f(gi[q][e] + gh[q][e]);
                        else { s_inn[i][j] = gi[q][e]; s_hnn[i][j] = gh[q][e]; }
                    }
                }
            }
        }
        __syncthreads();

        // ======== combine: deter_new = (1-z)*tanh(inn + r*hnn) + z*deter ========
        for (int idx = tid; idx < 16 * 200; idx += 1024) {
            int i = idx / 200, j = idx - i * 200;
            float rr = s_r[i][j], zz = s_z[i][j];
            float nn = tanhf(s_inn[i][j] + rr * s_hnn[i][j]);
            float d = (1.f - zz) * nn + zz * s_df[i][j];
            s_df[i][j] = d;
            s_db[cur ^ 1][i][j] = f2b(d);
        }
        __syncthreads();

        // ======== phase C: hq = elu(deter_new @ Wq1a^T + Epre) ========
        // early-issue next step's Epre/action loads (T14: consume in D2)
        float ep_a = 0.f, ep_b = 0.f, ep_c = 0.f, ep_d = 0.f, act_r = 0.f;
        const bool pA = (t + 1 < NT);
        if (pA) {
            const size_t tb = (size_t)(t + 1) * OC + 290;
            ep_a = out[(size_t)(b0 + i0) * NT * OC + tb + j0d];
            ep_b = out[(size_t)(b0 + i1) * NT * OC + tb + j1d];
            ep_c = out[(size_t)(b0 + i2) * NT * OC + tb + j2d];
            if (tid < 128) ep_d = out[(size_t)(b0 + i3) * NT * OC + tb + j3d];
            if (tid < 96)  act_r = action[((size_t)(b0 + ia) * NT + (t + 1)) * 6 + ca];
        }
        if (hasA) {
            f32x4 acc;
            #pragma unroll
            for (int e = 0; e < 4; ++e) acc[e] = s_ep[kgrp * 4 + e][jA];
            const size_t baseC = P_WQ1 + (size_t)(tA * 7) * 1024 + (size_t)ln * 8;
            #pragma unroll
            for (int ks = 0; ks < 7; ++ks) {
                short8 adn = *(const short8*)&s_db[cur ^ 1][arow][ks * 32 + kgrp * 8];
                short8 wf  = *(const short8*)&wp[baseC + (size_t)ks * 1024];
                acc = MFMA(adn, wf, acc);
            }
            #pragma unroll
            for (int e = 0; e < 4; ++e)
                s_hq[kgrp * 4 + e][jA] = f2b(elu_f(acc[e]));
        }
        __syncthreads();

        // ======== phase D1: q = hq @ Wq2^T + bq2 (waves 0-3) ========
        if (wv < 4) {
            f32x4 aq = {bD, bD, bD, bD};
            const size_t baseD = P_WQ2 + (size_t)(wv * 7) * 1024 + (size_t)ln * 8;
            #pragma unroll
            for (int ks = 0; ks < 7; ++ks) {
                short8 ah = *(const short8*)&s_hq[arow][ks * 32 + kgrp * 8];
                short8 wf = *(const short8*)&wp[baseD + (size_t)ks * 1024];
                aq = MFMA(ah, wf, aq);
            }
            #pragma unroll
            for (int e = 0; e < 4; ++e) s_q[kgrp * 4 + e][wv * 16 + arow] = aq[e];
        }
        __syncthreads();

        // ======== D2: sample + global writes + stage t+1 ========
        {
            if (tid < 480) {
                int i = tid / 30, ss = tid - i * 30;
                float qm = s_q[i][ss];
                float qs = sp_f(s_q[i][30 + ss]) + 0.1f;
                size_t bt = (size_t)(b0 + i) * NT + t;
                float qst = noise_post[bt * 30 + ss] * qs + qm;
                size_t o = bt * OC;
                out[o + ss]      = qm;
                out[o + 30 + ss] = qs;
                out[o + 60 + ss] = qst;
                s_in0[i][ss] = f2b(qst);
            }
            for (int idx = tid; idx < 16 * 200; idx += 1024) {
                int i = idx / 200, j = idx - i * 200;
                float d = s_df[i][j];
                size_t o = ((size_t)(b0 + i) * NT + t) * OC;
                out[o + 90 + j]  = d;
                out[o + 380 + j] = d;
            }
            if (pA) {
                s_ep[i0][j0d] = ep_a;
                s_ep[i1][j1d] = ep_b;
                s_ep[i2][j2d] = ep_c;
                if (tid < 128) s_ep[i3][j3d] = ep_d;
                if (tid < 96)  s_in0[ia][30 + ca] = f2b(act_r);
            }
            __syncthreads();
        }
        cur ^= 1;
    }
}

// ---------------------------------------------------------------------------
// Prior head (MFMA): 1024 blocks x 64 bt-rows, 256 thr (round-3 version)
// ---------------------------------------------------------------------------
__global__ __launch_bounds__(256) void prior_mfma(
    const float* __restrict__ noise_prior, const u16* __restrict__ wp,
    const float* __restrict__ bp1, const float* __restrict__ bp2,
    float* __restrict__ out)
{
    __shared__ __align__(16) u16   s_hp[64][232];
    __shared__ __align__(16) float s_p[64][68];
    const int tid = threadIdx.x;
    const int wv = tid >> 6, ln = tid & 63;
    const int arow = ln & 15, kgrp = ln >> 4;
    const size_t bt0 = (size_t)blockIdx.x * 64;
    const int m0 = wv * 16;

    for (int idx = tid; idx < 64 * 32; idx += 256) {   // zero pad cols 200..231
        int r2 = idx >> 5, c = 200 + (idx & 31);
        s_hp[r2][c] = 0;
    }

    // GEMM1: hp = elu(deter @ Wp1^T + bp1)
    f32x4 acc[13];
    #pragma unroll
    for (int tt = 0; tt < 13; ++tt) {
        const int j = tt * 16 + arow;
        const float bv = (j < 200) ? bp1[j] : 0.f;
        acc[tt] = (f32x4){bv, bv, bv, bv};
    }
    for (int ks = 0; ks < 7; ++ks) {
        short8 a;
        const int k0 = ks * 32 + kgrp * 8;
        if (k0 <= 192) {
            const float* dp = &out[(bt0 + m0 + arow) * OC + 380 + k0];
            float4 v0 = *(const float4*)dp;
            float4 v1 = *(const float4*)(dp + 4);
            a = pack8(v0, v1);
        } else {
            a = (short8){0, 0, 0, 0, 0, 0, 0, 0};
        }
        const u16* bp = &wp[P_WP1 + (size_t)ks * 13 * 1024 + (size_t)ln * 8];
        #pragma unroll
        for (int tt = 0; tt < 13; ++tt)
            acc[tt] = MFMA(a, *(const short8*)(bp + (size_t)tt * 1024), acc[tt]);
    }
    #pragma unroll
    for (int tt = 0; tt < 13; ++tt)
        #pragma unroll
        for (int e = 0; e < 4; ++e)
            s_hp[m0 + kgrp * 4 + e][tt * 16 + arow] = f2b(elu_f(acc[tt][e]));
    __syncthreads();

    // GEMM2: p = hp @ Wp2^T + bp2
    f32x4 acc2[4];
    #pragma unroll
    for (int tt = 0; tt < 4; ++tt) {
        const int j = tt * 16 + arow;
        const float bv = (j < 60) ? bp2[j] : 0.f;
        acc2[tt] = (f32x4){bv, bv, bv, bv};
    }
    #pragma unroll
    for (int ks = 0; ks < 7; ++ks) {
        short8 ah = *(const short8*)&s_hp[m0 + arow][ks * 32 + kgrp * 8];
        const u16* bp = &wp[P_WP2 + (size_t)ks * 4 * 1024 + (size_t)ln * 8];
        #pragma unroll
        for (int tt = 0; tt < 4; ++tt)
            acc2[tt] = MFMA(ah, *(const short8*)(bp + (size_t)tt * 1024), acc2[tt]);
    }
    #pragma unroll
    for (int tt = 0; tt < 4; ++tt)
        #pragma unroll
        for (int e = 0; e < 4; ++e)
            s_p[m0 + kgrp * 4 + e][tt * 16 + arow] = acc2[tt][e];
    __syncthreads();

    for (int idx = tid; idx < 64 * 30; idx += 256) {
        int i = idx / 30, ss = idx - i * 30;
        float pm = s_p[i][ss];
        float ps = sp_f(s_p[i][30 + ss]) + 0.1f;
        float pst = noise_prior[(bt0 + i) * 30 + ss] * ps + pm;
        size_t base = (bt0 + i) * OC;
        out[base + 290 + ss] = pm;
        out[base + 320 + ss] = ps;
        out[base + 350 + ss] = pst;
    }
}

extern "C" void kernel_launch(void* const* d_in, const int* in_sizes, int n_in,
                              void* d_out, int out_size, void* d_ws, size_t ws_size,
                              hipStream_t stream)
{
    (void)in_sizes; (void)n_in; (void)out_size; (void)ws_size;
    const float* embed       = (const float*)d_in[0];
    const float* action      = (const float*)d_in[1];
    const float* noise_prior = (const float*)d_in[2];
    const float* noise_post  = (const float*)d_in[3];
    const float* Wi   = (const float*)d_in[4];
    const float* bi   = (const float*)d_in[5];
    const float* W_ih = (const float*)d_in[6];
    const float* W_hh = (const float*)d_in[7];
    const float* b_ih = (const float*)d_in[8];
    const float* b_hh = (const float*)d_in[9];
    const float* Wp1  = (const float*)d_in[10];
    const float* bp1  = (const float*)d_in[11];
    const float* Wp2  = (const float*)d_in[12];
    const float* bp2  = (const float*)d_in[13];
    const float* Wq1  = (const float*)d_in[14];
    const float* bq1  = (const float*)d_in[15];
    const float* Wq2  = (const float*)d_in[16];
    const float* bq2  = (const float*)d_in[17];
    float* out = (float*)d_out;
    u16* wp = (u16*)d_ws;

    hipLaunchKernelGGL(prep_pack, dim3((P_TOTAL + 255) / 256), dim3(256), 0, stream,
                       Wi, W_ih, W_hh, Wq1, Wq2, Wp1, Wp2, wp);
    hipLaunchKernelGGL(epre_mfma, dim3(256), dim3(512), 0, stream,
                       embed, wp, bq1, out);
    hipLaunchKernelGGL(scan_mfma, dim3(64), dim3(1024), 0, stream,
                       action, noise_post, b_ih, b_hh, bi, bq2, wp, out);
    hipLaunchKernelGGL(prior_mfma, dim3(1024), dim3(256), 0, stream,
                       noise_prior, wp, bp1, bp2, out);
}

// Round 8
// 1542.774 us; speedup vs baseline: 2.3412x; 1.3149x over previous
//
#include <hip/hip_runtime.h>
#include <math.h>

typedef unsigned short u16;
typedef unsigned int   u32;
typedef __attribute__((ext_vector_type(8))) short short8;
typedef __attribute__((ext_vector_type(4))) float f32x4;

#define NBATCH 1024
#define NT 64
#define OC 580
#define RB 16            // batch rows per scan block
#define SCAN_BLOCKS (NBATCH / RB)
#define SX 232           // bf16 LDS row stride
#define SF 212           // f32 LDS row stride

// packed bf16 weight fragments (1024-u16 spacing, 512 used) in d_ws (u16 units)
#define P_WI    0        // [tt13][ks2]
#define P_WIH   26624    // [(g*13+tt)][ks7]
#define P_WHH   306176
#define P_WQ1   585728   // [tt13][ks7]
#define P_WQ2   678912   // [tt4][ks7]
#define P_EB    707584   // [ks32][tt13]
#define P_WP1   1133568  // [ks7][tt13]
#define P_WP2   1226752  // [ks7][tt4]
#define P_TOTAL 1255424

__device__ __forceinline__ float elu_f(float x) { return x > 0.f ? x : __expf(x) - 1.f; }
__device__ __forceinline__ float sig_f(float x) { return 1.f / (1.f + __expf(-x)); }
__device__ __forceinline__ float sp_f(float x)  { return x > 20.f ? x : log1pf(__expf(x)); }

__device__ __forceinline__ u16 f2b(float f) {   // f32 -> bf16 RNE
    union { float f; u32 u; } v; v.f = f;
    u32 r = (v.u + 0x7fffu + ((v.u >> 16) & 1u)) >> 16;
    return (u16)r;
}

__device__ __forceinline__ short8 pack8(float4 v0, float4 v1) {
    short8 r;
    r[0] = (short)f2b(v0.x); r[1] = (short)f2b(v0.y);
    r[2] = (short)f2b(v0.z); r[3] = (short)f2b(v0.w);
    r[4] = (short)f2b(v1.x); r[5] = (short)f2b(v1.y);
    r[6] = (short)f2b(v1.z); r[7] = (short)f2b(v1.w);
    return r;
}

#define MFMA(a, b, c) __builtin_amdgcn_mfma_f32_16x16x32_bf16((a), (b), (c), 0, 0, 0)

// ---------------------------------------------------------------------------
// prep: pack weights to bf16 MFMA B-fragment order:
// frag[lane][e] = W[n0 + (lane&15)][k0 + (lane>>4)*8 + e]  (0-padded)
// ---------------------------------------------------------------------------
__global__ __launch_bounds__(256) void prep_pack(
    const float* __restrict__ Wi, const float* __restrict__ W_ih,
    const float* __restrict__ W_hh, const float* __restrict__ Wq1,
    const float* __restrict__ Wq2, const float* __restrict__ Wp1,
    const float* __restrict__ Wp2, u16* __restrict__ wp)
{
    for (size_t r = (size_t)blockIdx.x * 256 + threadIdx.x; r < P_TOTAL;
         r += (size_t)gridDim.x * 256) {
        float val = 0.f;
        if (r < P_WIH) {                           // Wi: [200 x 36]
            int tile = r / 1024, lane = (r % 1024) / 8, el = r % 8;
            int tt = tile / 2, ks = tile % 2;
            int j = tt * 16 + (lane & 15), k = ks * 32 + (lane >> 4) * 8 + el;
            if (j < 200 && k < 36 && lane < 64) val = Wi[j * 36 + k];
        } else if (r < P_WHH) {                    // W_ih
            size_t q = r - P_WIH;
            int tile = q / 1024, lane = (q % 1024) / 8, el = q % 8;
            int g = tile / 91, rem = tile % 91, tt = rem / 7, ks = rem % 7;
            int j = tt * 16 + (lane & 15), k = ks * 32 + (lane >> 4) * 8 + el;
            if (j < 200 && k < 200 && lane < 64) val = W_ih[(size_t)(g * 200 + j) * 200 + k];
        } else if (r < P_WQ1) {                    // W_hh
            size_t q = r - P_WHH;
            int tile = q / 1024, lane = (q % 1024) / 8, el = q % 8;
            int g = tile / 91, rem = tile % 91, tt = rem / 7, ks = rem % 7;
            int j = tt * 16 + (lane & 15), k = ks * 32 + (lane >> 4) * 8 + el;
            if (j < 200 && k < 200 && lane < 64) val = W_hh[(size_t)(g * 200 + j) * 200 + k];
        } else if (r < P_WQ2) {                    // Wq1[:, :200]
            size_t q = r - P_WQ1;
            int tile = q / 1024, lane = (q % 1024) / 8, el = q % 8;
            int tt = tile / 7, ks = tile % 7;
            int j = tt * 16 + (lane & 15), k = ks * 32 + (lane >> 4) * 8 + el;
            if (j < 200 && k < 200 && lane < 64) val = Wq1[(size_t)j * 1224 + k];
        } else if (r < P_EB) {                     // Wq2: [60 x 200]
            size_t q = r - P_WQ2;
            int tile = q / 1024, lane = (q % 1024) / 8, el = q % 8;
            int tt = tile / 7, ks = tile % 7;
            int j = tt * 16 + (lane & 15), k = ks * 32 + (lane >> 4) * 8 + el;
            if (j < 60 && k < 200 && lane < 64) val = Wq2[(size_t)j * 200 + k];
        } else if (r < P_WP1) {                    // epre B: Wq1[:,200:1224]
            size_t q = r - P_EB;
            int tile = q / 1024, lane = (q % 1024) / 8, el = q % 8;
            int ks = tile / 13, tt = tile % 13;
            int j = tt * 16 + (lane & 15), k = ks * 32 + (lane >> 4) * 8 + el;
            if (j < 200 && lane < 64) val = Wq1[(size_t)j * 1224 + 200 + k];
        } else if (r < P_WP2) {                    // Wp1: [200 x 200]
            size_t q = r - P_WP1;
            int tile = q / 1024, lane = (q % 1024) / 8, el = q % 8;
            int ks = tile / 13, tt = tile % 13;
            int j = tt * 16 + (lane & 15), k = ks * 32 + (lane >> 4) * 8 + el;
            if (j < 200 && k < 200 && lane < 64) val = Wp1[(size_t)j * 200 + k];
        } else {                                   // Wp2: [60 x 200]
            size_t q = r - P_WP2;
            int tile = q / 1024, lane = (q % 1024) / 8, el = q % 8;
            int ks = tile / 4, tt = tile % 4;
            int j = tt * 16 + (lane & 15), k = ks * 32 + (lane >> 4) * 8 + el;
            if (j < 60 && k < 200 && lane < 64) val = Wp2[(size_t)j * 200 + k];
        }
        wp[r] = f2b(val);
    }
}

// ---------------------------------------------------------------------------
// Epre (MFMA): out[bt*580+290+j] = embed[bt] . Wq1[j][200:] + bq1[j]
// ---------------------------------------------------------------------------
__global__ __launch_bounds__(512) void epre_mfma(
    const float* __restrict__ embed, const u16* __restrict__ wp,
    const float* __restrict__ bq1, float* __restrict__ out)
{
    const int tid = threadIdx.x;
    const int wv = tid >> 6, ln = tid & 63;
    const int arow = ln & 15, kgrp = ln >> 4;
    const int m0 = blockIdx.x * 256 + wv * 32;

    f32x4 acc[2][13];
    #pragma unroll
    for (int tt = 0; tt < 13; ++tt) {
        const int j = tt * 16 + arow;
        const float bv = (j < 200) ? bq1[j] : 0.f;
        acc[0][tt] = (f32x4){bv, bv, bv, bv};
        acc[1][tt] = acc[0][tt];
    }
    const float* e0 = &embed[(size_t)(m0 + arow) * 1024 + kgrp * 8];
    const float* e1 = e0 + (size_t)16 * 1024;

    for (int ks = 0; ks < 32; ++ks) {
        short8 a0, a1;
        {
            float4 v0 = *(const float4*)(e0 + ks * 32);
            float4 v1 = *(const float4*)(e0 + ks * 32 + 4);
            a0 = pack8(v0, v1);
            float4 w0 = *(const float4*)(e1 + ks * 32);
            float4 w1 = *(const float4*)(e1 + ks * 32 + 4);
            a1 = pack8(w0, w1);
        }
        const u16* bp = &wp[P_EB + (size_t)ks * 13 * 1024 + (size_t)ln * 8];
        #pragma unroll
        for (int tt = 0; tt < 13; ++tt) {
            short8 b = *(const short8*)(bp + (size_t)tt * 1024);
            acc[0][tt] = MFMA(a0, b, acc[0][tt]);
            acc[1][tt] = MFMA(a1, b, acc[1][tt]);
        }
    }
    #pragma unroll
    for (int f = 0; f < 2; ++f) {
        const size_t rbase = (size_t)(m0 + f * 16 + kgrp * 4);
        #pragma unroll
        for (int tt = 0; tt < 13; ++tt) {
            const int j = tt * 16 + arow;
            if (j < 200) {
                #pragma unroll
                for (int e = 0; e < 4; ++e)
                    out[(rbase + e) * OC + 290 + j] = acc[f][tt][e];
            }
        }
    }
}

// ---------------------------------------------------------------------------
// MFMA scan: 64 blocks x 16 batch rows, 512 threads (8 waves) — round-2
// structure verbatim (proven: FETCH ~49MB, 1330 us).
// ---------------------------------------------------------------------------
__global__ __launch_bounds__(512) void scan_mfma(
    const float* __restrict__ action, const float* __restrict__ noise_post,
    const float* __restrict__ b_ih, const float* __restrict__ b_hh,
    const float* __restrict__ bi, const float* __restrict__ bq2,
    const u16* __restrict__ wp, float* __restrict__ out)
{
    __shared__ u16   s_in0[RB][72];           // [stoch30 | act6 | 0pad], K=64 used
    __shared__ u16   s_x[RB][SX];             // x bf16
    __shared__ u16   s_db[RB][SX];            // deter bf16 (MFMA shadow)
    __shared__ u16   s_hq[RB][SX];            // hq bf16
    __shared__ float s_df[RB][200];           // deter fp32 carry
    __shared__ float s_ep[RB][SF];            // Epre staged fp32
    __shared__ float s_r[RB][SF], s_z[RB][SF], s_inn[RB][SF], s_hnn[RB][SF];
    __shared__ float s_q[RB][64];
    __shared__ float s_bih[3][208], s_bhh[3][208], s_bi[208], s_bq2[64];

    const int tid  = threadIdx.x;
    const int wv   = tid >> 6, ln = tid & 63;
    const int arow = ln & 15, kgrp = ln >> 4;
    const int b0   = blockIdx.x * RB;

    // init: zero bf16 activations (incl. K-pads) + s_ep + s_df, stage biases
    { u32* z = (u32*)s_in0; for (int i = tid; i < RB*72/2;  i += 512) z[i] = 0; }
    { u32* z = (u32*)s_x;   for (int i = tid; i < RB*SX/2;  i += 512) z[i] = 0; }
    { u32* z = (u32*)s_db;  for (int i = tid; i < RB*SX/2;  i += 512) z[i] = 0; }
    { u32* z = (u32*)s_hq;  for (int i = tid; i < RB*SX/2;  i += 512) z[i] = 0; }
    { float* z = (float*)s_ep; for (int i = tid; i < RB*SF; i += 512) z[i] = 0.f; }
    { float* z = (float*)s_df; for (int i = tid; i < RB*200; i += 512) z[i] = 0.f; }
    for (int i = tid; i < 3 * 208; i += 512) {
        int g = i / 208, j = i % 208;
        s_bih[g][j] = j < 200 ? b_ih[g * 200 + j] : 0.f;
        s_bhh[g][j] = j < 200 ? b_hh[g * 200 + j] : 0.f;
    }
    for (int i = tid; i < 208; i += 512) s_bi[i] = i < 200 ? bi[i] : 0.f;
    if (tid < 64) s_bq2[tid] = tid < 60 ? bq2[tid] : 0.f;
    __syncthreads();

    for (int t = 0; t < NT; ++t) {
        // ---- stage Epre (16x200, written by epre_mfma) + action(t) ----
        for (int idx = tid; idx < RB * 200; idx += 512) {
            int i = idx / 200, j = idx % 200;
            s_ep[i][j] = out[((size_t)(b0 + i) * NT + t) * OC + 290 + j];
        }
        if (tid < RB * 6) {
            int i = tid / 6, c = tid % 6;
            s_in0[i][30 + c] = f2b(action[((size_t)(b0 + i) * NT + t) * 6 + c]);
        }
        __syncthreads();

        // ---- phase A: x = elu([stoch|act] @ Wi^T + bi), 13 n-tiles ----
        for (int tt = wv; tt < 13; tt += 8) {
            float bv = s_bi[tt * 16 + arow];
            f32x4 acc = {bv, bv, bv, bv};
            #pragma unroll
            for (int ks = 0; ks < 2; ++ks) {
                short8 af = *(const short8*)&s_in0[arow][ks * 32 + kgrp * 8];
                short8 wf = *(const short8*)&wp[P_WI + (size_t)(tt * 2 + ks) * 1024 + ln * 8];
                acc = MFMA(af, wf, acc);
            }
            #pragma unroll
            for (int e = 0; e < 4; ++e)
                s_x[kgrp * 4 + e][tt * 16 + arow] = f2b(elu_f(acc[e]));
        }
        __syncthreads();

        // ---- phase B: gi = x@W_ih^T, gh = deter@W_hh^T ; 39 (gate,tile) pairs ----
        {
            f32x4 gi[5], gh[5];
            #pragma unroll
            for (int q = 0; q < 5; ++q) {
                int p = wv + 8 * q; int pe = p < 39 ? p : 0;
                int g = pe / 13, tt = pe % 13;
                float b1 = s_bih[g][tt * 16 + arow];
                float b2 = s_bhh[g][tt * 16 + arow];
                gi[q] = (f32x4){b1, b1, b1, b1};
                gh[q] = (f32x4){b2, b2, b2, b2};
            }
            for (int ks = 0; ks < 7; ++ks) {
                short8 ax = *(const short8*)&s_x[arow][ks * 32 + kgrp * 8];
                short8 ad = *(const short8*)&s_db[arow][ks * 32 + kgrp * 8];
                #pragma unroll
                for (int q = 0; q < 5; ++q) {
                    int p = wv + 8 * q; int pe = p < 39 ? p : 0;
                    short8 w1 = *(const short8*)&wp[P_WIH + ((size_t)pe * 7 + ks) * 1024 + ln * 8];
                    short8 w2 = *(const short8*)&wp[P_WHH + ((size_t)pe * 7 + ks) * 1024 + ln * 8];
                    gi[q] = MFMA(ax, w1, gi[q]);
                    gh[q] = MFMA(ad, w2, gh[q]);
                }
            }
            #pragma unroll
            for (int q = 0; q < 5; ++q) {
                int p = wv + 8 * q;
                if (p < 39) {
                    int g = p / 13, tt = p % 13, j = tt * 16 + arow;
                    #pragma unroll
                    for (int e = 0; e < 4; ++e) {
                        int i = kgrp * 4 + e;
                        if (g == 0)      s_r[i][j] = sig_f(gi[q][e] + gh[q][e]);
                        else if (g == 1) s_z[i][j] = sig_f(gi[q][e] + gh[q][e]);
                        else { s_inn[i][j] = gi[q][e]; s_hnn[i][j] = gh[q][e]; }
                    }
                }
            }
        }
        __syncthreads();

        // ---- GRU combine: deter_new = (1-z)*tanh(inn + r*hnn) + z*deter ----
        for (int idx = tid; idx < RB * 200; idx += 512) {
            int i = idx / 200, j = idx % 200;
            float rr = s_r[i][j], zz = s_z[i][j];
            float nn = tanhf(s_inn[i][j] + rr * s_hnn[i][j]);
            float d = (1.f - zz) * nn + zz * s_df[i][j];
            s_df[i][j] = d;
            s_db[i][j] = f2b(d);
            size_t o = ((size_t)(b0 + i) * NT + t) * OC;
            out[o + 90 + j]  = d;   // post deter
            out[o + 380 + j] = d;   // prior deter
        }
        __syncthreads();

        // ---- phase C: hq = elu(deter_new @ Wq1a^T + Epre) ----
        for (int tt = wv; tt < 13; tt += 8) {
            int j = tt * 16 + arow;
            f32x4 acc;
            #pragma unroll
            for (int e = 0; e < 4; ++e) acc[e] = s_ep[kgrp * 4 + e][j];
            for (int ks = 0; ks < 7; ++ks) {
                short8 ad = *(const short8*)&s_db[arow][ks * 32 + kgrp * 8];
                short8 wf = *(const short8*)&wp[P_WQ1 + ((size_t)tt * 7 + ks) * 1024 + ln * 8];
                acc = MFMA(ad, wf, acc);
            }
            #pragma unroll
            for (int e = 0; e < 4; ++e)
                s_hq[kgrp * 4 + e][j] = f2b(elu_f(acc[e]));
        }
        __syncthreads();

        // ---- phase D1: q = hq @ Wq2^T + bq2 (4 n-tiles on waves 0-3) ----
        if (wv < 4) {
            int tt = wv, j = tt * 16 + arow;
            float bv = s_bq2[j];
            f32x4 acc = {bv, bv, bv, bv};
            for (int ks = 0; ks < 7; ++ks) {
                short8 ah = *(const short8*)&s_hq[arow][ks * 32 + kgrp * 8];
                short8 wf = *(const short8*)&wp[P_WQ2 + ((size_t)tt * 7 + ks) * 1024 + ln * 8];
                acc = MFMA(ah, wf, acc);
            }
            #pragma unroll
            for (int e = 0; e < 4; ++e) s_q[kgrp * 4 + e][j] = acc[e];
        }
        __syncthreads();

        // ---- phase D2: posterior sample + outputs + next stoch ----
        if (tid < RB * 30) {
            int i = tid / 30, s = tid % 30;
            float qm = s_q[i][s];
            float qs = sp_f(s_q[i][30 + s]) + 0.1f;
            size_t bt = (size_t)(b0 + i) * NT + t;
            float qst = noise_post[bt * 30 + s] * qs + qm;
            size_t o = bt * OC;
            out[o + s]      = qm;
            out[o + 30 + s] = qs;
            out[o + 60 + s] = qst;
            s_in0[i][s] = f2b(qst);
        }
        // no barrier needed: next stage writes disjoint LDS; barrier follows it
    }
}

// ---------------------------------------------------------------------------
// Prior head (MFMA): 1024 blocks x 64 bt-rows, 256 thr (4 waves x 16 rows).
// ---------------------------------------------------------------------------
__global__ __launch_bounds__(256) void prior_mfma(
    const float* __restrict__ noise_prior, const u16* __restrict__ wp,
    const float* __restrict__ bp1, const float* __restrict__ bp2,
    float* __restrict__ out)
{
    __shared__ __align__(16) u16   s_hp[64][232];
    __shared__ __align__(16) float s_p[64][68];
    const int tid = threadIdx.x;
    const int wv = tid >> 6, ln = tid & 63;
    const int arow = ln & 15, kgrp = ln >> 4;
    const size_t bt0 = (size_t)blockIdx.x * 64;
    const int m0 = wv * 16;

    for (int idx = tid; idx < 64 * 32; idx += 256) {   // zero pad cols 200..231
        int r2 = idx >> 5, c = 200 + (idx & 31);
        s_hp[r2][c] = 0;
    }

    // GEMM1: hp = elu(deter @ Wp1^T + bp1)
    f32x4 acc[13];
    #pragma unroll
    for (int tt = 0; tt < 13; ++tt) {
        const int j = tt * 16 + arow;
        const float bv = (j < 200) ? bp1[j] : 0.f;
        acc[tt] = (f32x4){bv, bv, bv, bv};
    }
    for (int ks = 0; ks < 7; ++ks) {
        short8 a;
        const int k0 = ks * 32 + kgrp * 8;
        if (k0 <= 192) {
            const float* dp = &out[(bt0 + m0 + arow) * OC + 380 + k0];
            float4 v0 = *(const float4*)dp;
            float4 v1 = *(const float4*)(dp + 4);
            a = pack8(v0, v1);
        } else {
            a = (short8){0, 0, 0, 0, 0, 0, 0, 0};
        }
        const u16* bp = &wp[P_WP1 + (size_t)ks * 13 * 1024 + (size_t)ln * 8];
        #pragma unroll
        for (int tt = 0; tt < 13; ++tt)
            acc[tt] = MFMA(a, *(const short8*)(bp + (size_t)tt * 1024), acc[tt]);
    }
    #pragma unroll
    for (int tt = 0; tt < 13; ++tt)
        #pragma unroll
        for (int e = 0; e < 4; ++e)
            s_hp[m0 + kgrp * 4 + e][tt * 16 + arow] = f2b(elu_f(acc[tt][e]));
    __syncthreads();

    // GEMM2: p = hp @ Wp2^T + bp2
    f32x4 acc2[4];
    #pragma unroll
    for (int tt = 0; tt < 4; ++tt) {
        const int j = tt * 16 + arow;
        const float bv = (j < 60) ? bp2[j] : 0.f;
        acc2[tt] = (f32x4){bv, bv, bv, bv};
    }
    #pragma unroll
    for (int ks = 0; ks < 7; ++ks) {
        short8 ah = *(const short8*)&s_hp[m0 + arow][ks * 32 + kgrp * 8];
        const u16* bp = &wp[P_WP2 + (size_t)ks * 4 * 1024 + (size_t)ln * 8];
        #pragma unroll
        for (int tt = 0; tt < 4; ++tt)
            acc2[tt] = MFMA(ah, *(const short8*)(bp + (size_t)tt * 1024), acc2[tt]);
    }
    #pragma unroll
    for (int tt = 0; tt < 4; ++tt)
        #pragma unroll
        for (int e = 0; e < 4; ++e)
            s_p[m0 + kgrp * 4 + e][tt * 16 + arow] = acc2[tt][e];
    __syncthreads();

    for (int idx = tid; idx < 64 * 30; idx += 256) {
        int i = idx / 30, ss = idx - i * 30;
        float pm = s_p[i][ss];
        float ps = sp_f(s_p[i][30 + ss]) + 0.1f;
        float pst = noise_prior[(bt0 + i) * 30 + ss] * ps + pm;
        size_t base = (bt0 + i) * OC;
        out[base + 290 + ss] = pm;
        out[base + 320 + ss] = ps;
        out[base + 350 + ss] = pst;
    }
}

extern "C" void kernel_launch(void* const* d_in, const int* in_sizes, int n_in,
                              void* d_out, int out_size, void* d_ws, size_t ws_size,
                              hipStream_t stream)
{
    (void)in_sizes; (void)n_in; (void)out_size; (void)ws_size;
    const float* embed       = (const float*)d_in[0];
    const float* action      = (const float*)d_in[1];
    const float* noise_prior = (const float*)d_in[2];
    const float* noise_post  = (const float*)d_in[3];
    const float* Wi   = (const float*)d_in[4];
    const float* bi   = (const float*)d_in[5];
    const float* W_ih = (const float*)d_in[6];
    const float* W_hh = (const float*)d_in[7];
    const float* b_ih = (const float*)d_in[8];
    const float* b_hh = (const float*)d_in[9];
    const float* Wp1  = (const float*)d_in[10];
    const float* bp1  = (const float*)d_in[11];
    const float* Wp2  = (const float*)d_in[12];
    const float* bp2  = (const float*)d_in[13];
    const float* Wq1  = (const float*)d_in[14];
    const float* bq1  = (const float*)d_in[15];
    const float* Wq2  = (const float*)d_in[16];
    const float* bq2  = (const float*)d_in[17];
    float* out = (float*)d_out;
    u16* wp = (u16*)d_ws;

    hipLaunchKernelGGL(prep_pack, dim3((P_TOTAL + 255) / 256), dim3(256), 0, stream,
                       Wi, W_ih, W_hh, Wq1, Wq2, Wp1, Wp2, wp);
    hipLaunchKernelGGL(epre_mfma, dim3(256), dim3(512), 0, stream,
                       embed, wp, bq1, out);
    hipLaunchKernelGGL(scan_mfma, dim3(SCAN_BLOCKS), dim3(512), 0, stream,
                       action, noise_post, b_ih, b_hh, bi, bq2, wp, out);
    hipLaunchKernelGGL(prior_mfma, dim3(NBATCH * NT / 64), dim3(256), 0, stream,
                       noise_prior, wp, bp1, bp2, out);
}

// Round 9
// 1482.405 us; speedup vs baseline: 2.4365x; 1.0407x over previous
//
#include <hip/hip_runtime.h>
#include <math.h>

typedef unsigned short u16;
typedef unsigned int   u32;
typedef __attribute__((ext_vector_type(8))) short short8;
typedef __attribute__((ext_vector_type(4))) float f32x4;

#define NBATCH 1024
#define NT 64
#define OC 580
#define RB 16            // batch rows per scan block
#define SCAN_BLOCKS (NBATCH / RB)
#define SX 232           // bf16 LDS row stride
#define SF 212           // f32 LDS row stride

// packed bf16 weight fragments (1024-u16 spacing, 512 used) in d_ws (u16 units)
#define P_WI    0        // [tt13][ks2]
#define P_WIH   26624    // [(g*13+tt)][ks7]
#define P_WHH   306176
#define P_WQ1   585728   // [tt13][ks7]
#define P_WQ2   678912   // [tt4][ks7]
#define P_EB    707584   // [ks32][tt13]
#define P_WP1   1133568  // [ks7][tt13]
#define P_WP2   1226752  // [ks7][tt4]
#define P_TOTAL 1255424

__device__ __forceinline__ float elu_f(float x) { return x > 0.f ? x : __expf(x) - 1.f; }
__device__ __forceinline__ float sig_f(float x) { return 1.f / (1.f + __expf(-x)); }
__device__ __forceinline__ float sp_f(float x)  { return x > 20.f ? x : log1pf(__expf(x)); }

__device__ __forceinline__ u16 f2b(float f) {   // f32 -> bf16 RNE
    union { float f; u32 u; } v; v.f = f;
    u32 r = (v.u + 0x7fffu + ((v.u >> 16) & 1u)) >> 16;
    return (u16)r;
}

__device__ __forceinline__ short8 pack8(float4 v0, float4 v1) {
    short8 r;
    r[0] = (short)f2b(v0.x); r[1] = (short)f2b(v0.y);
    r[2] = (short)f2b(v0.z); r[3] = (short)f2b(v0.w);
    r[4] = (short)f2b(v1.x); r[5] = (short)f2b(v1.y);
    r[6] = (short)f2b(v1.z); r[7] = (short)f2b(v1.w);
    return r;
}

#define MFMA(a, b, c) __builtin_amdgcn_mfma_f32_16x16x32_bf16((a), (b), (c), 0, 0, 0)

// ---------------------------------------------------------------------------
// prep: pack weights to bf16 MFMA B-fragment order:
// frag[lane][e] = W[n0 + (lane&15)][k0 + (lane>>4)*8 + e]  (0-padded)
// ---------------------------------------------------------------------------
__global__ __launch_bounds__(256) void prep_pack(
    const float* __restrict__ Wi, const float* __restrict__ W_ih,
    const float* __restrict__ W_hh, const float* __restrict__ Wq1,
    const float* __restrict__ Wq2, const float* __restrict__ Wp1,
    const float* __restrict__ Wp2, u16* __restrict__ wp)
{
    for (size_t r = (size_t)blockIdx.x * 256 + threadIdx.x; r < P_TOTAL;
         r += (size_t)gridDim.x * 256) {
        float val = 0.f;
        if (r < P_WIH) {                           // Wi: [200 x 36]
            int tile = r / 1024, lane = (r % 1024) / 8, el = r % 8;
            int tt = tile / 2, ks = tile % 2;
            int j = tt * 16 + (lane & 15), k = ks * 32 + (lane >> 4) * 8 + el;
            if (j < 200 && k < 36 && lane < 64) val = Wi[j * 36 + k];
        } else if (r < P_WHH) {                    // W_ih
            size_t q = r - P_WIH;
            int tile = q / 1024, lane = (q % 1024) / 8, el = q % 8;
            int g = tile / 91, rem = tile % 91, tt = rem / 7, ks = rem % 7;
            int j = tt * 16 + (lane & 15), k = ks * 32 + (lane >> 4) * 8 + el;
            if (j < 200 && k < 200 && lane < 64) val = W_ih[(size_t)(g * 200 + j) * 200 + k];
        } else if (r < P_WQ1) {                    // W_hh
            size_t q = r - P_WHH;
            int tile = q / 1024, lane = (q % 1024) / 8, el = q % 8;
            int g = tile / 91, rem = tile % 91, tt = rem / 7, ks = rem % 7;
            int j = tt * 16 + (lane & 15), k = ks * 32 + (lane >> 4) * 8 + el;
            if (j < 200 && k < 200 && lane < 64) val = W_hh[(size_t)(g * 200 + j) * 200 + k];
        } else if (r < P_WQ2) {                    // Wq1[:, :200]
            size_t q = r - P_WQ1;
            int tile = q / 1024, lane = (q % 1024) / 8, el = q % 8;
            int tt = tile / 7, ks = tile % 7;
            int j = tt * 16 + (lane & 15), k = ks * 32 + (lane >> 4) * 8 + el;
            if (j < 200 && k < 200 && lane < 64) val = Wq1[(size_t)j * 1224 + k];
        } else if (r < P_EB) {                     // Wq2: [60 x 200]
            size_t q = r - P_WQ2;
            int tile = q / 1024, lane = (q % 1024) / 8, el = q % 8;
            int tt = tile / 7, ks = tile % 7;
            int j = tt * 16 + (lane & 15), k = ks * 32 + (lane >> 4) * 8 + el;
            if (j < 60 && k < 200 && lane < 64) val = Wq2[(size_t)j * 200 + k];
        } else if (r < P_WP1) {                    // epre B: Wq1[:,200:1224]
            size_t q = r - P_EB;
            int tile = q / 1024, lane = (q % 1024) / 8, el = q % 8;
            int ks = tile / 13, tt = tile % 13;
            int j = tt * 16 + (lane & 15), k = ks * 32 + (lane >> 4) * 8 + el;
            if (j < 200 && lane < 64) val = Wq1[(size_t)j * 1224 + 200 + k];
        } else if (r < P_WP2) {                    // Wp1: [200 x 200]
            size_t q = r - P_WP1;
            int tile = q / 1024, lane = (q % 1024) / 8, el = q % 8;
            int ks = tile / 13, tt = tile % 13;
            int j = tt * 16 + (lane & 15), k = ks * 32 + (lane >> 4) * 8 + el;
            if (j < 200 && k < 200 && lane < 64) val = Wp1[(size_t)j * 200 + k];
        } else {                                   // Wp2: [60 x 200]
            size_t q = r - P_WP2;
            int tile = q / 1024, lane = (q % 1024) / 8, el = q % 8;
            int ks = tile / 4, tt = tile % 4;
            int j = tt * 16 + (lane & 15), k = ks * 32 + (lane >> 4) * 8 + el;
            if (j < 60 && k < 200 && lane < 64) val = Wp2[(size_t)j * 200 + k];
        }
        wp[r] = f2b(val);
    }
}

// ---------------------------------------------------------------------------
// Epre (MFMA): out[bt*580+290+j] = embed[bt] . Wq1[j][200:] + bq1[j]
// ---------------------------------------------------------------------------
__global__ __launch_bounds__(512) void epre_mfma(
    const float* __restrict__ embed, const u16* __restrict__ wp,
    const float* __restrict__ bq1, float* __restrict__ out)
{
    const int tid = threadIdx.x;
    const int wv = tid >> 6, ln = tid & 63;
    const int arow = ln & 15, kgrp = ln >> 4;
    const int m0 = blockIdx.x * 256 + wv * 32;

    f32x4 acc[2][13];
    #pragma unroll
    for (int tt = 0; tt < 13; ++tt) {
        const int j = tt * 16 + arow;
        const float bv = (j < 200) ? bq1[j] : 0.f;
        acc[0][tt] = (f32x4){bv, bv, bv, bv};
        acc[1][tt] = acc[0][tt];
    }
    const float* e0 = &embed[(size_t)(m0 + arow) * 1024 + kgrp * 8];
    const float* e1 = e0 + (size_t)16 * 1024;

    for (int ks = 0; ks < 32; ++ks) {
        short8 a0, a1;
        {
            float4 v0 = *(const float4*)(e0 + ks * 32);
            float4 v1 = *(const float4*)(e0 + ks * 32 + 4);
            a0 = pack8(v0, v1);
            float4 w0 = *(const float4*)(e1 + ks * 32);
            float4 w1 = *(const float4*)(e1 + ks * 32 + 4);
            a1 = pack8(w0, w1);
        }
        const u16* bp = &wp[P_EB + (size_t)ks * 13 * 1024 + (size_t)ln * 8];
        #pragma unroll
        for (int tt = 0; tt < 13; ++tt) {
            short8 b = *(const short8*)(bp + (size_t)tt * 1024);
            acc[0][tt] = MFMA(a0, b, acc[0][tt]);
            acc[1][tt] = MFMA(a1, b, acc[1][tt]);
        }
    }
    #pragma unroll
    for (int f = 0; f < 2; ++f) {
        const size_t rbase = (size_t)(m0 + f * 16 + kgrp * 4);
        #pragma unroll
        for (int tt = 0; tt < 13; ++tt) {
            const int j = tt * 16 + arow;
            if (j < 200) {
                #pragma unroll
                for (int e = 0; e < 4; ++e)
                    out[(rbase + e) * OC + 290 + j] = acc[f][tt][e];
            }
        }
    }
}

// ---------------------------------------------------------------------------
// MFMA scan: 64 blocks x 16 batch rows, 512 threads (8 waves).
// Round-8 structure + __launch_bounds__(512,2) (256-VGPR cap, same occupancy:
// LDS already limits to 1 block/CU = 2 waves/SIMD) + W_hh fragments held
// persistently in registers across the t-loop (35 x short8/wave, static idx).
// ---------------------------------------------------------------------------
__global__ __launch_bounds__(512, 2) void scan_mfma(
    const float* __restrict__ action, const float* __restrict__ noise_post,
    const float* __restrict__ b_ih, const float* __restrict__ b_hh,
    const float* __restrict__ bi, const float* __restrict__ bq2,
    const u16* __restrict__ wp, float* __restrict__ out)
{
    __shared__ u16   s_in0[RB][72];           // [stoch30 | act6 | 0pad], K=64 used
    __shared__ u16   s_x[RB][SX];             // x bf16
    __shared__ u16   s_db[RB][SX];            // deter bf16 (MFMA shadow)
    __shared__ u16   s_hq[RB][SX];            // hq bf16
    __shared__ float s_df[RB][200];           // deter fp32 carry
    __shared__ float s_ep[RB][SF];            // Epre staged fp32
    __shared__ float s_r[RB][SF], s_z[RB][SF], s_inn[RB][SF], s_hnn[RB][SF];
    __shared__ float s_q[RB][64];
    __shared__ float s_bih[3][208], s_bhh[3][208], s_bi[208], s_bq2[64];

    const int tid  = threadIdx.x;
    const int wv   = tid >> 6, ln = tid & 63;
    const int arow = ln & 15, kgrp = ln >> 4;
    const int b0   = blockIdx.x * RB;

    // init: zero bf16 activations (incl. K-pads) + s_ep + s_df, stage biases
    { u32* z = (u32*)s_in0; for (int i = tid; i < RB*72/2;  i += 512) z[i] = 0; }
    { u32* z = (u32*)s_x;   for (int i = tid; i < RB*SX/2;  i += 512) z[i] = 0; }
    { u32* z = (u32*)s_db;  for (int i = tid; i < RB*SX/2;  i += 512) z[i] = 0; }
    { u32* z = (u32*)s_hq;  for (int i = tid; i < RB*SX/2;  i += 512) z[i] = 0; }
    { float* z = (float*)s_ep; for (int i = tid; i < RB*SF; i += 512) z[i] = 0.f; }
    { float* z = (float*)s_df; for (int i = tid; i < RB*200; i += 512) z[i] = 0.f; }
    for (int i = tid; i < 3 * 208; i += 512) {
        int g = i / 208, j = i % 208;
        s_bih[g][j] = j < 200 ? b_ih[g * 200 + j] : 0.f;
        s_bhh[g][j] = j < 200 ? b_hh[g * 200 + j] : 0.f;
    }
    for (int i = tid; i < 208; i += 512) s_bi[i] = i < 200 ? bi[i] : 0.f;
    if (tid < 64) s_bq2[tid] = tid < 60 ? bq2[tid] : 0.f;

    // ---- persistent W_hh fragments: 5 units x 7 ks, hoisted out of t-loop ----
    short8 whhP[5][7];
    #pragma unroll
    for (int q = 0; q < 5; ++q) {
        int p = wv + 8 * q; int pe = p < 39 ? p : 0;
        #pragma unroll
        for (int ks = 0; ks < 7; ++ks)
            whhP[q][ks] = *(const short8*)&wp[P_WHH + ((size_t)pe * 7 + ks) * 1024 + ln * 8];
    }
    __syncthreads();

    for (int t = 0; t < NT; ++t) {
        // ---- stage Epre (16x200, written by epre_mfma) + action(t) ----
        for (int idx = tid; idx < RB * 200; idx += 512) {
            int i = idx / 200, j = idx % 200;
            s_ep[i][j] = out[((size_t)(b0 + i) * NT + t) * OC + 290 + j];
        }
        if (tid < RB * 6) {
            int i = tid / 6, c = tid % 6;
            s_in0[i][30 + c] = f2b(action[((size_t)(b0 + i) * NT + t) * 6 + c]);
        }
        __syncthreads();

        // ---- phase A: x = elu([stoch|act] @ Wi^T + bi), 13 n-tiles ----
        for (int tt = wv; tt < 13; tt += 8) {
            float bv = s_bi[tt * 16 + arow];
            f32x4 acc = {bv, bv, bv, bv};
            #pragma unroll
            for (int ks = 0; ks < 2; ++ks) {
                short8 af = *(const short8*)&s_in0[arow][ks * 32 + kgrp * 8];
                short8 wf = *(const short8*)&wp[P_WI + (size_t)(tt * 2 + ks) * 1024 + ln * 8];
                acc = MFMA(af, wf, acc);
            }
            #pragma unroll
            for (int e = 0; e < 4; ++e)
                s_x[kgrp * 4 + e][tt * 16 + arow] = f2b(elu_f(acc[e]));
        }
        __syncthreads();

        // ---- phase B: gi = x@W_ih^T (inline), gh = deter@W_hh^T (registers) ----
        {
            f32x4 gi[5], gh[5];
            #pragma unroll
            for (int q = 0; q < 5; ++q) {
                int p = wv + 8 * q; int pe = p < 39 ? p : 0;
                int g = pe / 13, tt = pe % 13;
                float b1 = s_bih[g][tt * 16 + arow];
                float b2 = s_bhh[g][tt * 16 + arow];
                gi[q] = (f32x4){b1, b1, b1, b1};
                gh[q] = (f32x4){b2, b2, b2, b2};
            }
            #pragma unroll
            for (int ks = 0; ks < 7; ++ks) {
                short8 ax = *(const short8*)&s_x[arow][ks * 32 + kgrp * 8];
                short8 ad = *(const short8*)&s_db[arow][ks * 32 + kgrp * 8];
                #pragma unroll
                for (int q = 0; q < 5; ++q) {
                    int p = wv + 8 * q; int pe = p < 39 ? p : 0;
                    short8 w1 = *(const short8*)&wp[P_WIH + ((size_t)pe * 7 + ks) * 1024 + ln * 8];
                    gi[q] = MFMA(ax, w1, gi[q]);
                    gh[q] = MFMA(ad, whhP[q][ks], gh[q]);
                }
            }
            #pragma unroll
            for (int q = 0; q < 5; ++q) {
                int p = wv + 8 * q;
                if (p < 39) {
                    int g = p / 13, tt = p % 13, j = tt * 16 + arow;
                    #pragma unroll
                    for (int e = 0; e < 4; ++e) {
                        int i = kgrp * 4 + e;
                        if (g == 0)      s_r[i][j] = sig_f(gi[q][e] + gh[q][e]);
                        else if (g == 1) s_z[i][j] = sig_f(gi[q][e] + gh[q][e]);
                        else { s_inn[i][j] = gi[q][e]; s_hnn[i][j] = gh[q][e]; }
                    }
                }
            }
        }
        __syncthreads();

        // ---- GRU combine: deter_new = (1-z)*tanh(inn + r*hnn) + z*deter ----
        for (int idx = tid; idx < RB * 200; idx += 512) {
            int i = idx / 200, j = idx % 200;
            float rr = s_r[i][j], zz = s_z[i][j];
            float nn = tanhf(s_inn[i][j] + rr * s_hnn[i][j]);
            float d = (1.f - zz) * nn + zz * s_df[i][j];
            s_df[i][j] = d;
            s_db[i][j] = f2b(d);
            size_t o = ((size_t)(b0 + i) * NT + t) * OC;
            out[o + 90 + j]  = d;   // post deter
            out[o + 380 + j] = d;   // prior deter
        }
        __syncthreads();

        // ---- phase C: hq = elu(deter_new @ Wq1a^T + Epre) ----
        for (int tt = wv; tt < 13; tt += 8) {
            int j = tt * 16 + arow;
            f32x4 acc;
            #pragma unroll
            for (int e = 0; e < 4; ++e) acc[e] = s_ep[kgrp * 4 + e][j];
            for (int ks = 0; ks < 7; ++ks) {
                short8 ad = *(const short8*)&s_db[arow][ks * 32 + kgrp * 8];
                short8 wf = *(const short8*)&wp[P_WQ1 + ((size_t)tt * 7 + ks) * 1024 + ln * 8];
                acc = MFMA(ad, wf, acc);
            }
            #pragma unroll
            for (int e = 0; e < 4; ++e)
                s_hq[kgrp * 4 + e][j] = f2b(elu_f(acc[e]));
        }
        __syncthreads();

        // ---- phase D1: q = hq @ Wq2^T + bq2 (4 n-tiles on waves 0-3) ----
        if (wv < 4) {
            int tt = wv, j = tt * 16 + arow;
            float bv = s_bq2[j];
            f32x4 acc = {bv, bv, bv, bv};
            for (int ks = 0; ks < 7; ++ks) {
                short8 ah = *(const short8*)&s_hq[arow][ks * 32 + kgrp * 8];
                short8 wf = *(const short8*)&wp[P_WQ2 + ((size_t)tt * 7 + ks) * 1024 + ln * 8];
                acc = MFMA(ah, wf, acc);
            }
            #pragma unroll
            for (int e = 0; e < 4; ++e) s_q[kgrp * 4 + e][j] = acc[e];
        }
        __syncthreads();

        // ---- phase D2: posterior sample + outputs + next stoch ----
        if (tid < RB * 30) {
            int i = tid / 30, s = tid % 30;
            float qm = s_q[i][s];
            float qs = sp_f(s_q[i][30 + s]) + 0.1f;
            size_t bt = (size_t)(b0 + i) * NT + t;
            float qst = noise_post[bt * 30 + s] * qs + qm;
            size_t o = bt * OC;
            out[o + s]      = qm;
            out[o + 30 + s] = qs;
            out[o + 60 + s] = qst;
            s_in0[i][s] = f2b(qst);
        }
        // no barrier needed: next stage writes disjoint LDS; barrier follows it
    }
}

// ---------------------------------------------------------------------------
// Prior head (MFMA): 1024 blocks x 64 bt-rows, 256 thr (4 waves x 16 rows).
// ---------------------------------------------------------------------------
__global__ __launch_bounds__(256) void prior_mfma(
    const float* __restrict__ noise_prior, const u16* __restrict__ wp,
    const float* __restrict__ bp1, const float* __restrict__ bp2,
    float* __restrict__ out)
{
    __shared__ __align__(16) u16   s_hp[64][232];
    __shared__ __align__(16) float s_p[64][68];
    const int tid = threadIdx.x;
    const int wv = tid >> 6, ln = tid & 63;
    const int arow = ln & 15, kgrp = ln >> 4;
    const size_t bt0 = (size_t)blockIdx.x * 64;
    const int m0 = wv * 16;

    for (int idx = tid; idx < 64 * 32; idx += 256) {   // zero pad cols 200..231
        int r2 = idx >> 5, c = 200 + (idx & 31);
        s_hp[r2][c] = 0;
    }

    // GEMM1: hp = elu(deter @ Wp1^T + bp1)
    f32x4 acc[13];
    #pragma unroll
    for (int tt = 0; tt < 13; ++tt) {
        const int j = tt * 16 + arow;
        const float bv = (j < 200) ? bp1[j] : 0.f;
        acc[tt] = (f32x4){bv, bv, bv, bv};
    }
    for (int ks = 0; ks < 7; ++ks) {
        short8 a;
        const int k0 = ks * 32 + kgrp * 8;
        if (k0 <= 192) {
            const float* dp = &out[(bt0 + m0 + arow) * OC + 380 + k0];
            float4 v0 = *(const float4*)dp;
            float4 v1 = *(const float4*)(dp + 4);
            a = pack8(v0, v1);
        } else {
            a = (short8){0, 0, 0, 0, 0, 0, 0, 0};
        }
        const u16* bp = &wp[P_WP1 + (size_t)ks * 13 * 1024 + (size_t)ln * 8];
        #pragma unroll
        for (int tt = 0; tt < 13; ++tt)
            acc[tt] = MFMA(a, *(const short8*)(bp + (size_t)tt * 1024), acc[tt]);
    }
    #pragma unroll
    for (int tt = 0; tt < 13; ++tt)
        #pragma unroll
        for (int e = 0; e < 4; ++e)
            s_hp[m0 + kgrp * 4 + e][tt * 16 + arow] = f2b(elu_f(acc[tt][e]));
    __syncthreads();

    // GEMM2: p = hp @ Wp2^T + bp2
    f32x4 acc2[4];
    #pragma unroll
    for (int tt = 0; tt < 4; ++tt) {
        const int j = tt * 16 + arow;
        const float bv = (j < 60) ? bp2[j] : 0.f;
        acc2[tt] = (f32x4){bv, bv, bv, bv};
    }
    #pragma unroll
    for (int ks = 0; ks < 7; ++ks) {
        short8 ah = *(const short8*)&s_hp[m0 + arow][ks * 32 + kgrp * 8];
        const u16* bp = &wp[P_WP2 + (size_t)ks * 4 * 1024 + (size_t)ln * 8];
        #pragma unroll
        for (int tt = 0; tt < 4; ++tt)
            acc2[tt] = MFMA(ah, *(const short8*)(bp + (size_t)tt * 1024), acc2[tt]);
    }
    #pragma unroll
    for (int tt = 0; tt < 4; ++tt)
        #pragma unroll
        for (int e = 0; e < 4; ++e)
            s_p[m0 + kgrp * 4 + e][tt * 16 + arow] = acc2[tt][e];
    __syncthreads();

    for (int idx = tid; idx < 64 * 30; idx += 256) {
        int i = idx / 30, ss = idx - i * 30;
        float pm = s_p[i][ss];
        float ps = sp_f(s_p[i][30 + ss]) + 0.1f;
        float pst = noise_prior[(bt0 + i) * 30 + ss] * ps + pm;
        size_t base = (bt0 + i) * OC;
        out[base + 290 + ss] = pm;
        out[base + 320 + ss] = ps;
        out[base + 350 + ss] = pst;
    }
}

extern "C" void kernel_launch(void* const* d_in, const int* in_sizes, int n_in,
                              void* d_out, int out_size, void* d_ws, size_t ws_size,
                              hipStream_t stream)
{
    (void)in_sizes; (void)n_in; (void)out_size; (void)ws_size;
    const float* embed       = (const float*)d_in[0];
    const float* action      = (const float*)d_in[1];
    const float* noise_prior = (const float*)d_in[2];
    const float* noise_post  = (const float*)d_in[3];
    const float* Wi   = (const float*)d_in[4];
    const float* bi   = (const float*)d_in[5];
    const float* W_ih = (const float*)d_in[6];
    const float* W_hh = (const float*)d_in[7];
    const float* b_ih = (const float*)d_in[8];
    const float* b_hh = (const float*)d_in[9];
    const float* Wp1  = (const float*)d_in[10];
    const float* bp1  = (const float*)d_in[11];
    const float* Wp2  = (const float*)d_in[12];
    const float* bp2  = (const float*)d_in[13];
    const float* Wq1  = (const float*)d_in[14];
    const float* bq1  = (const float*)d_in[15];
    const float* Wq2  = (const float*)d_in[16];
    const float* bq2  = (const float*)d_in[17];
    float* out = (float*)d_out;
    u16* wp = (u16*)d_ws;

    hipLaunchKernelGGL(prep_pack, dim3((P_TOTAL + 255) / 256), dim3(256), 0, stream,
                       Wi, W_ih, W_hh, Wq1, Wq2, Wp1, Wp2, wp);
    hipLaunchKernelGGL(epre_mfma, dim3(256), dim3(512), 0, stream,
                       embed, wp, bq1, out);
    hipLaunchKernelGGL(scan_mfma, dim3(SCAN_BLOCKS), dim3(512), 0, stream,
                       action, noise_post, b_ih, b_hh, bi, bq2, wp, out);
    hipLaunchKernelGGL(prior_mfma, dim3(NBATCH * NT / 64), dim3(256), 0, stream,
                       noise_prior, wp, bp1, bp2, out);
}